// Round 1
// baseline (1150.240 us; speedup 1.0000x reference)
//
#include <hip/hip_runtime.h>
#include <hip/hip_bf16.h>

// Geometry constants
#define NPHI 720
#define NT   512
#define NH   256
#define NB   32

#define DPHI_F   0.004363323129985824f   // pi/720
#define INV_DT_F 181.01933598375618f     // 256/sqrt(2)
#define DX_F     0.0078125f              // 2/256
#define W2PI_F   0.012271846303085130f   // 2*pi/512

// ---------------------------------------------------------------------------
// Kernel A: build h = irfft(K, 512) (real even 512-tap) and the angle table.
// ws layout (floats): [0,512) h ; [512, 512+2880) trig {c/DT, s/DT, c*DX/DT, s*DX/DT}
// ---------------------------------------------------------------------------
__global__ void build_tables_kernel(const float* __restrict__ kern,
                                    float* __restrict__ ws) {
    __shared__ float ctab[512];
    __shared__ float kk[257];
    const int t = threadIdx.x;            // 512 threads
    if (t < 257) kk[t] = kern[t];
    ctab[t] = cosf((float)t * W2PI_F);
    __syncthreads();

    float acc = 0.f;
    for (int k = 1; k < 256; ++k)
        acc += kk[k] * ctab[(k * t) & 511];
    float h = (kk[0] + ((t & 1) ? -kk[256] : kk[256]) + 2.f * acc) * (1.f / 512.f);
    ws[t] = h;

    for (int p = t; p < NPHI; p += 512) {
        float ang = ((float)p + 0.5f) * DPHI_F;
        float s, c;
        sincosf(ang, &s, &c);
        float cd = c * INV_DT_F;
        float sd = s * INV_DT_F;
        ws[512 + 4 * p + 0] = cd;
        ws[512 + 4 * p + 1] = sd;
        ws[512 + 4 * p + 2] = cd * DX_F;
        ws[512 + 4 * p + 3] = sd * DX_F;
    }
}

// ---------------------------------------------------------------------------
// Kernel B: circular convolution filtered[row, i] = sum_m h[m] * g[row, (i-m)%512]
// One wave per row (4 rows per 256-thread block). Each lane produces 8
// consecutive outputs via a 16-float register window, m unrolled by 8.
// FMA-bound: 64 fma per (wave, 8-m block).
// ---------------------------------------------------------------------------
__global__ __launch_bounds__(256) void conv_kernel(const float* __restrict__ g,
                                                   const float* __restrict__ hws,
                                                   float* __restrict__ filt) {
    __shared__ float gg[4][1024];   // doubled rows for circular indexing
    __shared__ float hs[512];
    const int tid = threadIdx.x;
    hs[tid]       = hws[tid];
    hs[tid + 256] = hws[tid + 256];

    const int r = tid >> 6;          // wave id = row within block
    const int l = tid & 63;          // lane
    const long long row = (long long)blockIdx.x * 4 + r;

    const float4* gsrc = (const float4*)(g + row * NT);
    float4 a0 = gsrc[2 * l];
    float4 a1 = gsrc[2 * l + 1];
    *(float4*)&gg[r][8 * l]           = a0;
    *(float4*)&gg[r][8 * l + 4]       = a1;
    *(float4*)&gg[r][512 + 8 * l]     = a0;
    *(float4*)&gg[r][512 + 8 * l + 4] = a1;
    __syncthreads();

    float acc[8] = {0.f, 0.f, 0.f, 0.f, 0.f, 0.f, 0.f, 0.f};

    #pragma unroll 1
    for (int m0 = 0; m0 < 512; m0 += 8) {
        float w[16], hh[8];
        const int a = 8 * l + 504 - m0;     // multiple of 8 -> 16B aligned
        *(float4*)&w[0]  = *(const float4*)&gg[r][a];
        *(float4*)&w[4]  = *(const float4*)&gg[r][a + 4];
        *(float4*)&w[8]  = *(const float4*)&gg[r][a + 8];
        *(float4*)&w[12] = *(const float4*)&gg[r][a + 12];
        *(float4*)&hh[0] = *(const float4*)&hs[m0];
        *(float4*)&hh[4] = *(const float4*)&hs[m0 + 4];
        #pragma unroll
        for (int dm = 0; dm < 8; ++dm) {
            #pragma unroll
            for (int rr = 0; rr < 8; ++rr) {
                // output o = 8l+rr, tap m = m0+dm, gg index = o - m + 512 = a + 8 - dm + rr
                acc[rr] += hh[dm] * w[8 - dm + rr];
            }
        }
    }

    float4 o0 = make_float4(acc[0], acc[1], acc[2], acc[3]);
    float4 o1 = make_float4(acc[4], acc[5], acc[6], acc[7]);
    float* orow = filt + row * NT + 8 * l;
    *(float4*)orow       = o0;
    *(float4*)(orow + 4) = o1;
}

// ---------------------------------------------------------------------------
// Kernel C: backprojection. Block = (batch, 64x64 image tile), 256 threads,
// each thread owns a 4x4 pixel patch. Angles staged 8 at a time into
// zero-padded LDS rows (row[-1] = row[512] = 0 -> branch-free clipped lerp).
// ---------------------------------------------------------------------------
__global__ __launch_bounds__(256) void backproject_kernel(const float* __restrict__ filt,
                                                          const float* __restrict__ ws,
                                                          float* __restrict__ out) {
    __shared__ float trig[NPHI * 4];          // 11.25 KB
    __shared__ float rowsbuf[8 * 520 + 8];    // 8 rows, stride 520, +8 front pad
    float* rows0 = rowsbuf + 8;

    const int tid  = threadIdx.x;
    const int b    = blockIdx.x >> 4;
    const int tile = blockIdx.x & 15;
    const int ibase = (tile >> 2) * 64;
    const int jbase = (tile & 3) * 64;

    for (int idx = tid; idx < NPHI * 4; idx += 256)
        trig[idx] = ws[512 + idx];
    // zero pads: rows0[c*520 + 512..519] (covers row c tail AND row c+1's [-1])
    if (tid < 64) {
        int c = tid >> 3, k = tid & 7;
        rows0[c * 520 + 512 + k] = 0.f;
    } else if (tid < 72) {
        rowsbuf[tid - 64] = 0.f;              // covers rows0[-1] for c = 0
    }

    const int tx = tid & 15;
    const int ty = tid >> 4;
    const float xi = -1.f + ((float)(ibase + ty * 4) + 0.5f) * DX_F;
    const float yj = -1.f + ((float)(jbase + tx * 4) + 0.5f) * DX_F;

    float acc[4][4];
    #pragma unroll
    for (int a = 0; a < 4; ++a)
        #pragma unroll
        for (int c = 0; c < 4; ++c) acc[a][c] = 0.f;

    const float* fb = filt + (size_t)b * (NPHI * NT);
    const int cc  = tid >> 5;                 // staging row 0..7
    const int off = (tid & 31) * 16;          // 32 threads cover 512 floats

    for (int p0 = 0; p0 < NPHI; p0 += 8) {
        __syncthreads();   // previous chunk's compute done (also covers init)
        const float4* src = (const float4*)(fb + (size_t)(p0 + cc) * NT + off);
        float4 v0 = src[0], v1 = src[1], v2 = src[2], v3 = src[3];
        float* dst = rows0 + cc * 520 + off;
        *(float4*)(dst)      = v0;
        *(float4*)(dst + 4)  = v1;
        *(float4*)(dst + 8)  = v2;
        *(float4*)(dst + 12) = v3;
        __syncthreads();

        #pragma unroll
        for (int c2 = 0; c2 < 8; ++c2) {
            const int p = p0 + c2;
            const float cd  = trig[4 * p + 0];
            const float sd  = trig[4 * p + 1];
            const float dci = trig[4 * p + 2];
            const float dsj = trig[4 * p + 3];
            const float* rowp = rows0 + c2 * 520;
            float ur = xi * cd + yj * sd + 255.5f;
            #pragma unroll
            for (int di = 0; di < 4; ++di) {
                float u = ur;
                #pragma unroll
                for (int dj = 0; dj < 4; ++dj) {
                    float fl = floorf(u);
                    int   ii = (int)fl;       // in [-1, 511]
                    float w  = u - fl;
                    float a0 = rowp[ii];
                    float a1 = rowp[ii + 1];
                    acc[di][dj] += a0 + w * (a1 - a0);
                    u += dsj;
                }
                ur += dci;
            }
        }
    }

    float* ob = out + (size_t)b * (NH * NH) + (size_t)(ibase + ty * 4) * NH + (jbase + tx * 4);
    #pragma unroll
    for (int di = 0; di < 4; ++di) {
        float4 o = make_float4(acc[di][0] * DPHI_F, acc[di][1] * DPHI_F,
                               acc[di][2] * DPHI_F, acc[di][3] * DPHI_F);
        *(float4*)(ob + di * NH) = o;
    }
}

// ---------------------------------------------------------------------------
extern "C" void kernel_launch(void* const* d_in, const int* in_sizes, int n_in,
                              void* d_out, int out_size, void* d_ws, size_t ws_size,
                              hipStream_t stream) {
    const float* sinos = (const float*)d_in[0];   // [32,720,512] f32
    const float* kern  = (const float*)d_in[1];   // [257] f32
    float* out = (float*)d_out;                   // [32,256,256] f32
    float* ws  = (float*)d_ws;

    float* filt = ws + 4096;   // 32*720*512 floats = 47.2 MB

    hipLaunchKernelGGL(build_tables_kernel, dim3(1), dim3(512), 0, stream, kern, ws);
    hipLaunchKernelGGL(conv_kernel, dim3((NB * NPHI) / 4), dim3(256), 0, stream,
                       sinos, ws, filt);
    hipLaunchKernelGGL(backproject_kernel, dim3(NB * 16), dim3(256), 0, stream,
                       filt, ws, out);
}

// Round 2
// 593.942 us; speedup vs baseline: 1.9366x; 1.9366x over previous
//
#include <hip/hip_runtime.h>
#include <hip/hip_bf16.h>

// Geometry constants
#define NPHI 720
#define NT   512
#define NH   256
#define NB   32

#define DPHI_F   0.004363323129985824f   // pi/720
#define INV_DT_F 181.01933598375618f     // 256/sqrt(2)
#define DX_F     0.0078125f              // 2/256
#define W2PI_F   0.012271846303085130f   // 2*pi/512

// ---------------------------------------------------------------------------
// Kernel A: build h = irfft(K, 512) (real even 512-tap) and the angle table.
// ws layout (floats): [0,512) h ; [512, 512+2880) trig {c/DT, s/DT, c*DX/DT, s*DX/DT}
// ---------------------------------------------------------------------------
__global__ void build_tables_kernel(const float* __restrict__ kern,
                                    float* __restrict__ ws) {
    __shared__ float ctab[512];
    __shared__ float kk[257];
    const int t = threadIdx.x;            // 512 threads
    if (t < 257) kk[t] = kern[t];
    ctab[t] = cosf((float)t * W2PI_F);
    __syncthreads();

    float acc = 0.f;
    for (int k = 1; k < 256; ++k)
        acc += kk[k] * ctab[(k * t) & 511];
    float h = (kk[0] + ((t & 1) ? -kk[256] : kk[256]) + 2.f * acc) * (1.f / 512.f);
    ws[t] = h;

    for (int p = t; p < NPHI; p += 512) {
        float ang = ((float)p + 0.5f) * DPHI_F;
        float s, c;
        sincosf(ang, &s, &c);
        float cd = c * INV_DT_F;
        float sd = s * INV_DT_F;
        ws[512 + 4 * p + 0] = cd;
        ws[512 + 4 * p + 1] = sd;
        ws[512 + 4 * p + 2] = cd * DX_F;
        ws[512 + 4 * p + 3] = sd * DX_F;
    }
}

// ---------------------------------------------------------------------------
// Kernel B: circular conv, transposed schedule (rows-as-lanes).
// Block = 256 thr, stages 8 rows doubled into LDS (stride 1044 floats so
// bank-quad = (5r + 4*(c&1) + j) mod 8 is uniform -> conflict-free b128).
// Lane (r = tid&7, c = tid>>3) computes outputs [16c, 16c+16) of row r via a
// 32-float sliding register window (two 16-float halves, roles swap per iter).
// filtered[o] = sum_m h[m] * g[(o-m) mod 512];  doubled index D = o0+512-m0.
// ---------------------------------------------------------------------------
#define CSTR 1044

#define LOAD16(dst, srcp) { \
    *(float4*)&(dst)[0]  = *(const float4*)&(srcp)[0];  \
    *(float4*)&(dst)[4]  = *(const float4*)&(srcp)[4];  \
    *(float4*)&(dst)[8]  = *(const float4*)&(srcp)[8];  \
    *(float4*)&(dst)[12] = *(const float4*)&(srcp)[12]; }

__global__ __launch_bounds__(256, 4) void conv_kernel(const float* __restrict__ g,
                                                      const float* __restrict__ hws,
                                                      float* __restrict__ filt) {
    __shared__ __attribute__((aligned(16))) float gld[8 * CSTR];
    __shared__ __attribute__((aligned(16))) float hls[512];
    const int tid = threadIdx.x;

    *(float2*)&hls[tid * 2] = *(const float2*)&hws[tid * 2];

    const long long rowbase = (long long)blockIdx.x * 8;
    const float4* gs = (const float4*)(g + rowbase * NT);
    #pragma unroll
    for (int k = 0; k < 4; ++k) {
        int q = tid + 256 * k;            // 0..1023
        int r = q >> 7, pos = q & 127;    // 128 float4 per row
        float4 v = gs[r * 128 + pos];
        *(float4*)&gld[r * CSTR + pos * 4]       = v;
        *(float4*)&gld[r * CSTR + 512 + pos * 4] = v;
    }
    __syncthreads();

    const int r  = tid & 7;
    const int c  = tid >> 3;        // 0..31
    const int o0 = c * 16;
    const float* row = &gld[r * CSTR];

    float acc[16];
    #pragma unroll
    for (int j = 0; j < 16; ++j) acc[j] = 0.f;

    float wA[16], wB[16], hh[16];
    // prologue, m0 = 0: D = o0+512; lo=[D-16,D-1]->wA, hi=[D,D+15]->wB
    LOAD16(wA, row + o0 + 496);
    LOAD16(wB, row + o0 + 512);

    #pragma unroll 1
    for (int m00 = 0; m00 < 512; m00 += 32) {
        // iter A: m0 = m00, lo=wA, hi=wB
        LOAD16(hh, hls + m00);
        #pragma unroll
        for (int dm = 0; dm < 16; ++dm)
            #pragma unroll
            for (int j = 0; j < 16; ++j) {
                float x = (j >= dm) ? wB[j - dm] : wA[16 + j - dm];
                acc[j] = fmaf(hh[dm], x, acc[j]);
            }
        // preload lo for iter B (m0 = m00+16): [D_B-16, D_B-1] = [o0+480-m00, +15]
        LOAD16(wB, row + o0 + 480 - m00);
        LOAD16(hh, hls + m00 + 16);
        // iter B: lo = wB (new), hi = wA (old lo)
        #pragma unroll
        for (int dm = 0; dm < 16; ++dm)
            #pragma unroll
            for (int j = 0; j < 16; ++j) {
                float x = (j >= dm) ? wA[j - dm] : wB[16 + j - dm];
                acc[j] = fmaf(hh[dm], x, acc[j]);
            }
        if (m00 < 480) LOAD16(wA, row + o0 + 464 - m00);  // lo for next A
    }

    float* dst = filt + (rowbase + r) * NT + o0;
    *(float4*)&dst[0]  = make_float4(acc[0],  acc[1],  acc[2],  acc[3]);
    *(float4*)&dst[4]  = make_float4(acc[4],  acc[5],  acc[6],  acc[7]);
    *(float4*)&dst[8]  = make_float4(acc[8],  acc[9],  acc[10], acc[11]);
    *(float4*)&dst[12] = make_float4(acc[12], acc[13], acc[14], acc[15]);
}

// ---------------------------------------------------------------------------
// Kernel C: backprojection. Grid = 32 batches x 32 tiles (32i x 64j) = 1024
// blocks (exactly 4/CU). 256 thr: 4 waves, each a 16x32 footprint (8x8 lanes
// of 2x4 patches) -> per-instr LDS address spread <= ~45 -> ~no conflicts.
// Angles staged 4/chunk as dup-float2 rows: drow[k] = (row[k-1], row[k]),
// k in [0,513); lerp = one aligned ds_read_b64: v = s.x + w*(s.y - s.x).
// Staging: sr = tid&3 (row), sk = tid>>2 (8-float segment) -> conflict-free
// float4 LDS writes (bank-quad = sr + 4*(sk&1) + t covers all 8).
// ---------------------------------------------------------------------------
__global__ __launch_bounds__(256, 4) void backproject_kernel(const float* __restrict__ filt,
                                                             const float* __restrict__ ws,
                                                             float* __restrict__ out) {
    __shared__ __attribute__((aligned(16))) float2 rows[4 * 514];

    const int tid  = threadIdx.x;
    const int bidx = (int)blockIdx.x;
    const int b    = bidx >> 5;
    const int tile = bidx & 31;            // 8 x 4 tiles of 32x64
    const int i0 = (tile >> 2) * 32;
    const int j0 = (tile & 3) * 64;

    const int w  = tid >> 6;
    const int l  = tid & 63;
    const int wi = (w >> 1) * 16, wj = (w & 1) * 32;
    const int li = l >> 3, lj = l & 7;
    const int pi = i0 + wi + 2 * li;       // patch rows pi, pi+1
    const int pj = j0 + wj + 4 * lj;       // patch cols pj..pj+3
    const float xi = -1.f + ((float)pi + 0.5f) * DX_F;
    const float yj = -1.f + ((float)pj + 0.5f) * DX_F;

    float acc[2][4];
    #pragma unroll
    for (int di = 0; di < 2; ++di)
        #pragma unroll
        for (int dj = 0; dj < 4; ++dj) acc[di][dj] = 0.f;

    const float* fb   = filt + (size_t)b * (NPHI * NT);
    const float* trig = ws + 512;
    const int sr = tid & 3;                // staging row
    const int sk = tid >> 2;               // 0..63, 8-float segment

    for (int p0 = 0; p0 < NPHI; p0 += 4) {
        __syncthreads();
        const float* src = fb + (size_t)(p0 + sr) * NT + sk * 8;
        float4 v0 = *(const float4*)src;
        float4 v1 = *(const float4*)(src + 4);
        float prev = (sk == 0) ? 0.f : src[-1];
        float pr[9] = {prev, v0.x, v0.y, v0.z, v0.w, v1.x, v1.y, v1.z, v1.w};
        float2* drow = rows + sr * 514;
        #pragma unroll
        for (int t = 0; t < 4; ++t)
            *(float4*)&drow[8 * sk + 2 * t] =
                make_float4(pr[2*t], pr[2*t+1], pr[2*t+1], pr[2*t+2]);
        if (sk == 63) drow[512] = make_float2(pr[8], 0.f);
        __syncthreads();

        #pragma unroll
        for (int a = 0; a < 4; ++a) {
            const float4 tg = *(const float4*)&trig[(p0 + a) * 4]; // cd,sd,dci,dsj
            const float2* dr = rows + a * 514;
            // u' = u + 1 so dup index ip = floor(u)+1 in [0,512]
            const float u0 = xi * tg.x + yj * tg.y + 256.5f;
            #pragma unroll
            for (int di = 0; di < 2; ++di) {
                float u = di ? (u0 + tg.z) : u0;
                #pragma unroll
                for (int dj = 0; dj < 4; ++dj) {
                    float fl = floorf(u);
                    float wwv = u - fl;
                    int ip = (int)fl;
                    float2 s = dr[ip];
                    acc[di][dj] += s.x + wwv * (s.y - s.x);
                    u += tg.w;
                }
            }
        }
    }

    float* ob = out + (size_t)b * (NH * NH) + (size_t)pi * NH + pj;
    #pragma unroll
    for (int di = 0; di < 2; ++di) {
        float4 o = make_float4(acc[di][0] * DPHI_F, acc[di][1] * DPHI_F,
                               acc[di][2] * DPHI_F, acc[di][3] * DPHI_F);
        *(float4*)(ob + di * NH) = o;
    }
}

// ---------------------------------------------------------------------------
extern "C" void kernel_launch(void* const* d_in, const int* in_sizes, int n_in,
                              void* d_out, int out_size, void* d_ws, size_t ws_size,
                              hipStream_t stream) {
    const float* sinos = (const float*)d_in[0];   // [32,720,512] f32
    const float* kern  = (const float*)d_in[1];   // [257] f32
    float* out = (float*)d_out;                   // [32,256,256] f32
    float* ws  = (float*)d_ws;

    float* filt = ws + 4096;   // 32*720*512 floats = 47.2 MB

    hipLaunchKernelGGL(build_tables_kernel, dim3(1), dim3(512), 0, stream, kern, ws);
    hipLaunchKernelGGL(conv_kernel, dim3((NB * NPHI) / 8), dim3(256), 0, stream,
                       sinos, ws, filt);
    hipLaunchKernelGGL(backproject_kernel, dim3(NB * 32), dim3(256), 0, stream,
                       filt, ws, out);
}

// Round 5
// 433.573 us; speedup vs baseline: 2.6529x; 1.3699x over previous
//
#include <hip/hip_runtime.h>
#include <hip/hip_bf16.h>

// Geometry constants
#define NPHI 720
#define NT   512
#define NH   256
#define NB   32

#define DPHI_F   0.004363323129985824f   // pi/720
#define INV_DT_F 181.01933598375618f     // 256/sqrt(2)
#define DX_F     0.0078125f              // 2/256
#define W2PI_F   0.012271846303085130f   // 2*pi/512

// ---------------------------------------------------------------------------
// Kernel A: build h = irfft(K, 512) (real even 512-tap) and the angle table.
// ws layout (floats): [0,512) h ; [512, 512+2880) trig {c/DT, s/DT, c*DX/DT, s*DX/DT}
// ---------------------------------------------------------------------------
__global__ void build_tables_kernel(const float* __restrict__ kern,
                                    float* __restrict__ ws) {
    __shared__ float ctab[512];
    __shared__ float kk[257];
    const int t = threadIdx.x;            // 512 threads
    if (t < 257) kk[t] = kern[t];
    ctab[t] = cosf((float)t * W2PI_F);
    __syncthreads();

    float acc = 0.f;
    for (int k = 1; k < 256; ++k)
        acc += kk[k] * ctab[(k * t) & 511];
    float h = (kk[0] + ((t & 1) ? -kk[256] : kk[256]) + 2.f * acc) * (1.f / 512.f);
    ws[t] = h;

    for (int p = t; p < NPHI; p += 512) {
        float ang = ((float)p + 0.5f) * DPHI_F;
        float s, c;
        sincosf(ang, &s, &c);
        float cd = c * INV_DT_F;
        float sd = s * INV_DT_F;
        ws[512 + 4 * p + 0] = cd;
        ws[512 + 4 * p + 1] = sd;
        ws[512 + 4 * p + 2] = cd * DX_F;
        ws[512 + 4 * p + 3] = sd * DX_F;
    }
}

// ---------------------------------------------------------------------------
// Kernel B: circular conv, transposed schedule (rows-as-lanes).
// ~at fp32 FMA roofline (~77 us ideal) -- leave alone.
// ---------------------------------------------------------------------------
#define CSTR 1044

#define LOAD16(dst, srcp) { \
    *(float4*)&(dst)[0]  = *(const float4*)&(srcp)[0];  \
    *(float4*)&(dst)[4]  = *(const float4*)&(srcp)[4];  \
    *(float4*)&(dst)[8]  = *(const float4*)&(srcp)[8];  \
    *(float4*)&(dst)[12] = *(const float4*)&(srcp)[12]; }

__global__ __launch_bounds__(256, 4) void conv_kernel(const float* __restrict__ g,
                                                      const float* __restrict__ hws,
                                                      float* __restrict__ filt) {
    __shared__ __attribute__((aligned(16))) float gld[8 * CSTR];
    __shared__ __attribute__((aligned(16))) float hls[512];
    const int tid = threadIdx.x;

    *(float2*)&hls[tid * 2] = *(const float2*)&hws[tid * 2];

    const long long rowbase = (long long)blockIdx.x * 8;
    const float4* gs = (const float4*)(g + rowbase * NT);
    #pragma unroll
    for (int k = 0; k < 4; ++k) {
        int q = tid + 256 * k;            // 0..1023
        int r = q >> 7, pos = q & 127;    // 128 float4 per row
        float4 v = gs[r * 128 + pos];
        *(float4*)&gld[r * CSTR + pos * 4]       = v;
        *(float4*)&gld[r * CSTR + 512 + pos * 4] = v;
    }
    __syncthreads();

    const int r  = tid & 7;
    const int c  = tid >> 3;        // 0..31
    const int o0 = c * 16;
    const float* row = &gld[r * CSTR];

    float acc[16];
    #pragma unroll
    for (int j = 0; j < 16; ++j) acc[j] = 0.f;

    float wA[16], wB[16], hh[16];
    LOAD16(wA, row + o0 + 496);
    LOAD16(wB, row + o0 + 512);

    #pragma unroll 1
    for (int m00 = 0; m00 < 512; m00 += 32) {
        LOAD16(hh, hls + m00);
        #pragma unroll
        for (int dm = 0; dm < 16; ++dm)
            #pragma unroll
            for (int j = 0; j < 16; ++j) {
                float x = (j >= dm) ? wB[j - dm] : wA[16 + j - dm];
                acc[j] = fmaf(hh[dm], x, acc[j]);
            }
        LOAD16(wB, row + o0 + 480 - m00);
        LOAD16(hh, hls + m00 + 16);
        #pragma unroll
        for (int dm = 0; dm < 16; ++dm)
            #pragma unroll
            for (int j = 0; j < 16; ++j) {
                float x = (j >= dm) ? wA[j - dm] : wB[16 + j - dm];
                acc[j] = fmaf(hh[dm], x, acc[j]);
            }
        if (m00 < 480) LOAD16(wA, row + o0 + 464 - m00);
    }

    float* dst = filt + (rowbase + r) * NT + o0;
    *(float4*)&dst[0]  = make_float4(acc[0],  acc[1],  acc[2],  acc[3]);
    *(float4*)&dst[4]  = make_float4(acc[4],  acc[5],  acc[6],  acc[7]);
    *(float4*)&dst[8]  = make_float4(acc[8],  acc[9],  acc[10], acc[11]);
    *(float4*)&dst[12] = make_float4(acc[12], acc[13], acc[14], acc[15]);
}

// ---------------------------------------------------------------------------
// Kernel C: backprojection v3 -- windowed staging + 2 batches per block.
// Grid = 16 batch-pairs x 64 tiles (32x32 px) = 1024 blocks (4/CU).
//   [R4 fix: launch was dim3(NB*16)=512 -- decomposition b=(bidx>>6)*2,
//    tile=bidx&63 needs 1024 blocks; batches 16-31 were never written.]
// Per 16-angle chunk: stage, per (angle,batch), an 80-slot dup-float2 window
//   win[s] = (row[b0+s-1], row[b0+s]) zero-clamped, b0 = floor(umin over tile
//   corners) - 1 (tile u-span <= 62 cells so 80 slots always cover).
// Index convention (verified R1): ip = floor(q + 256.5) into full dup-row;
//   window shift: ip_win = floor(q + cst), cst = 256.5 - b0  [R3 fix].
// Compute: lane owns 2x2 px patch x 2 batches; address math shared across
//   batches -- two ds_read_b64 from one vaddr (batch-1 via offset immediate).
// Wave footprint 16x16 px -> u spread <= 28 slots -> ~conflict-free.
// ---------------------------------------------------------------------------
#define WCHUNK 16
#define WSTR   82
#define BOFF   (WCHUNK * WSTR)    // float2 offset between batch windows

__global__ __launch_bounds__(256, 4) void backproject_kernel(const float* __restrict__ filt,
                                                             const float* __restrict__ ws,
                                                             float* __restrict__ out) {
    __shared__ __attribute__((aligned(16))) float2 win[2 * WCHUNK * WSTR];
    __shared__ float cstbuf[WCHUNK];

    const int tid  = threadIdx.x;
    const int bidx = (int)blockIdx.x;
    const int b    = (bidx >> 6) * 2;      // batches b, b+1
    const int tile = bidx & 63;            // 8 x 8 tiles of 32x32
    const int i0 = (tile >> 3) * 32;
    const int j0 = (tile & 7) * 32;

    // compute-phase pixel mapping: wave = 16x16 px, lane = 2x2 px patch
    const int w  = tid >> 6;
    const int l  = tid & 63;
    const int wi = (w >> 1) * 16, wj = (w & 1) * 16;
    const int li = l >> 3, lj = l & 7;
    const int pi = i0 + wi + 2 * li;
    const int pj = j0 + wj + 2 * lj;
    const float xi = -1.f + ((float)pi + 0.5f) * DX_F;
    const float yj = -1.f + ((float)pj + 0.5f) * DX_F;

    // staging mapping: 16 threads per angle
    const int sa = tid >> 4;
    const int st = tid & 15;
    const float xlo = -1.f + ((float)i0 + 0.5f) * DX_F;
    const float xhi = xlo + 31.f * DX_F;
    const float ylo = -1.f + ((float)j0 + 0.5f) * DX_F;
    const float yhi = ylo + 31.f * DX_F;

    const float* fb0  = filt + (size_t)b * (NPHI * NT);
    const float* trig = ws + 512;

    float acc[2][2][2];
    #pragma unroll
    for (int bb = 0; bb < 2; ++bb)
        #pragma unroll
        for (int di = 0; di < 2; ++di)
            #pragma unroll
            for (int dj = 0; dj < 2; ++dj) acc[bb][di][dj] = 0.f;

    for (int p0 = 0; p0 < NPHI; p0 += WCHUNK) {
        __syncthreads();
        {
            const int p = p0 + sa;
            const float4 tg = *(const float4*)&trig[p * 4];
            const float umin = 256.5f + fminf(xlo * tg.x, xhi * tg.x)
                                      + fminf(ylo * tg.y, yhi * tg.y);
            const float b0f = floorf(umin) - 1.f;
            if (st == 0) cstbuf[sa] = 256.5f - b0f;
            const int base = (int)b0f + 5 * st - 1;
            const float* r0 = fb0 + (size_t)p * NT;
            float2* wrow = win + sa * WSTR + 5 * st;
            #pragma unroll
            for (int bb = 0; bb < 2; ++bb) {
                const float* rr = r0 + (size_t)bb * (NPHI * NT);
                float f[6];
                #pragma unroll
                for (int k = 0; k < 6; ++k) {
                    int idx = base + k;
                    f[k] = ((unsigned)idx < 512u) ? rr[idx] : 0.f;
                }
                float2* wr = wrow + bb * BOFF;
                #pragma unroll
                for (int j = 0; j < 5; ++j)
                    wr[j] = make_float2(f[j], f[j + 1]);
            }
        }
        __syncthreads();

        #pragma unroll 2
        for (int a = 0; a < WCHUNK; ++a) {
            const float4 tg = *(const float4*)&trig[(p0 + a) * 4]; // cd,sd,dci,dsj
            const float cst = cstbuf[a];
            const float2* wr = win + a * WSTR;
            const float u00 = xi * tg.x + yj * tg.y + cst;
            #pragma unroll
            for (int di = 0; di < 2; ++di) {
                float u = di ? (u00 + tg.z) : u00;
                #pragma unroll
                for (int dj = 0; dj < 2; ++dj) {
                    float fl = floorf(u);
                    float ww = u - fl;
                    int ip = (int)fl;
                    float2 s0 = wr[ip];
                    float2 s1 = wr[ip + BOFF];
                    acc[0][di][dj] += s0.x + ww * (s0.y - s0.x);
                    acc[1][di][dj] += s1.x + ww * (s1.y - s1.x);
                    u += tg.w;
                }
            }
        }
    }

    #pragma unroll
    for (int bb = 0; bb < 2; ++bb) {
        float* ob = out + (size_t)(b + bb) * (NH * NH) + (size_t)pi * NH + pj;
        #pragma unroll
        for (int di = 0; di < 2; ++di) {
            float2 o = make_float2(acc[bb][di][0] * DPHI_F, acc[bb][di][1] * DPHI_F);
            *(float2*)(ob + di * NH) = o;
        }
    }
}

// ---------------------------------------------------------------------------
extern "C" void kernel_launch(void* const* d_in, const int* in_sizes, int n_in,
                              void* d_out, int out_size, void* d_ws, size_t ws_size,
                              hipStream_t stream) {
    const float* sinos = (const float*)d_in[0];   // [32,720,512] f32
    const float* kern  = (const float*)d_in[1];   // [257] f32
    float* out = (float*)d_out;                   // [32,256,256] f32
    float* ws  = (float*)d_ws;

    float* filt = ws + 4096;   // 32*720*512 floats = 47.2 MB

    hipLaunchKernelGGL(build_tables_kernel, dim3(1), dim3(512), 0, stream, kern, ws);
    hipLaunchKernelGGL(conv_kernel, dim3((NB * NPHI) / 8), dim3(256), 0, stream,
                       sinos, ws, filt);
    hipLaunchKernelGGL(backproject_kernel, dim3((NB / 2) * 64), dim3(256), 0, stream,
                       filt, ws, out);
}

// Round 6
// 418.233 us; speedup vs baseline: 2.7502x; 1.0367x over previous
//
#include <hip/hip_runtime.h>
#include <hip/hip_bf16.h>

// Geometry constants
#define NPHI 720
#define NT   512
#define NH   256
#define NB   32

#define DPHI_F   0.004363323129985824f   // pi/720
#define INV_DT_F 181.01933598375618f     // 256/sqrt(2)
#define DX_F     0.0078125f              // 2/256
#define W2PI_F   0.012271846303085130f   // 2*pi/512

// ---------------------------------------------------------------------------
// Kernel A: build h = irfft(K, 512) (real even 512-tap) and the angle table.
// ws layout (floats): [0,512) h ; [512, 512+2880) trig {c/DT, s/DT, c*DX/DT, s*DX/DT}
// ---------------------------------------------------------------------------
__global__ void build_tables_kernel(const float* __restrict__ kern,
                                    float* __restrict__ ws) {
    __shared__ float ctab[512];
    __shared__ float kk[257];
    const int t = threadIdx.x;            // 512 threads
    if (t < 257) kk[t] = kern[t];
    ctab[t] = cosf((float)t * W2PI_F);
    __syncthreads();

    float acc = 0.f;
    for (int k = 1; k < 256; ++k)
        acc += kk[k] * ctab[(k * t) & 511];
    float h = (kk[0] + ((t & 1) ? -kk[256] : kk[256]) + 2.f * acc) * (1.f / 512.f);
    ws[t] = h;

    for (int p = t; p < NPHI; p += 512) {
        float ang = ((float)p + 0.5f) * DPHI_F;
        float s, c;
        sincosf(ang, &s, &c);
        float cd = c * INV_DT_F;
        float sd = s * INV_DT_F;
        ws[512 + 4 * p + 0] = cd;
        ws[512 + 4 * p + 1] = sd;
        ws[512 + 4 * p + 2] = cd * DX_F;
        ws[512 + 4 * p + 3] = sd * DX_F;
    }
}

// ---------------------------------------------------------------------------
// Kernel B: circular conv, transposed schedule (rows-as-lanes).
// ~at fp32 FMA roofline (~77 us ideal) -- leave alone.
// ---------------------------------------------------------------------------
#define CSTR 1044

#define LOAD16(dst, srcp) { \
    *(float4*)&(dst)[0]  = *(const float4*)&(srcp)[0];  \
    *(float4*)&(dst)[4]  = *(const float4*)&(srcp)[4];  \
    *(float4*)&(dst)[8]  = *(const float4*)&(srcp)[8];  \
    *(float4*)&(dst)[12] = *(const float4*)&(srcp)[12]; }

__global__ __launch_bounds__(256, 4) void conv_kernel(const float* __restrict__ g,
                                                      const float* __restrict__ hws,
                                                      float* __restrict__ filt) {
    __shared__ __attribute__((aligned(16))) float gld[8 * CSTR];
    __shared__ __attribute__((aligned(16))) float hls[512];
    const int tid = threadIdx.x;

    *(float2*)&hls[tid * 2] = *(const float2*)&hws[tid * 2];

    const long long rowbase = (long long)blockIdx.x * 8;
    const float4* gs = (const float4*)(g + rowbase * NT);
    #pragma unroll
    for (int k = 0; k < 4; ++k) {
        int q = tid + 256 * k;            // 0..1023
        int r = q >> 7, pos = q & 127;    // 128 float4 per row
        float4 v = gs[r * 128 + pos];
        *(float4*)&gld[r * CSTR + pos * 4]       = v;
        *(float4*)&gld[r * CSTR + 512 + pos * 4] = v;
    }
    __syncthreads();

    const int r  = tid & 7;
    const int c  = tid >> 3;        // 0..31
    const int o0 = c * 16;
    const float* row = &gld[r * CSTR];

    float acc[16];
    #pragma unroll
    for (int j = 0; j < 16; ++j) acc[j] = 0.f;

    float wA[16], wB[16], hh[16];
    LOAD16(wA, row + o0 + 496);
    LOAD16(wB, row + o0 + 512);

    #pragma unroll 1
    for (int m00 = 0; m00 < 512; m00 += 32) {
        LOAD16(hh, hls + m00);
        #pragma unroll
        for (int dm = 0; dm < 16; ++dm)
            #pragma unroll
            for (int j = 0; j < 16; ++j) {
                float x = (j >= dm) ? wB[j - dm] : wA[16 + j - dm];
                acc[j] = fmaf(hh[dm], x, acc[j]);
            }
        LOAD16(wB, row + o0 + 480 - m00);
        LOAD16(hh, hls + m00 + 16);
        #pragma unroll
        for (int dm = 0; dm < 16; ++dm)
            #pragma unroll
            for (int j = 0; j < 16; ++j) {
                float x = (j >= dm) ? wA[j - dm] : wB[16 + j - dm];
                acc[j] = fmaf(hh[dm], x, acc[j]);
            }
        if (m00 < 480) LOAD16(wA, row + o0 + 464 - m00);
    }

    float* dst = filt + (rowbase + r) * NT + o0;
    *(float4*)&dst[0]  = make_float4(acc[0],  acc[1],  acc[2],  acc[3]);
    *(float4*)&dst[4]  = make_float4(acc[4],  acc[5],  acc[6],  acc[7]);
    *(float4*)&dst[8]  = make_float4(acc[8],  acc[9],  acc[10], acc[11]);
    *(float4*)&dst[12] = make_float4(acc[12], acc[13], acc[14], acc[15]);
}

// ---------------------------------------------------------------------------
// Kernel C: backprojection v4 -- 4 batches per block, paired-batch float4
// windows, split accumulators, trig table in LDS.
// Grid = 8 batch-quads x 64 tiles (32x32 px) = 512 blocks (2/CU; LDS 54KB).
// Window: win[a][p][s] = (lo,hi of batch 2p | lo,hi of batch 2p+1) where
//   lo = row[b0+s-1], hi = row[b0+s], b0 = floor(umin over tile corners)-1.
// Index convention (R1/R3-verified): ip = floor(q + cst), cst = 256.5 - b0;
//   ip in [1,65] subset of [0,80). One ds_read_b128 at win[a][0][ip] serves
//   batches 0,1; second at +WSTR*16B (offset immediate) serves batches 2,3.
// Lerp: accL += (1-w)*lo, accH += w*hi -> exactly 2 fma/sample; combine at
//   epilogue: out = (accL+accH)*DPHI.
// ---------------------------------------------------------------------------
#define WCHUNK 16
#define WSTR   82

__global__ __launch_bounds__(256, 2) void backproject_kernel(const float* __restrict__ filt,
                                                             const float* __restrict__ ws,
                                                             float* __restrict__ out) {
    __shared__ __attribute__((aligned(16))) float4 win[WCHUNK][2][WSTR];
    __shared__ __attribute__((aligned(16))) float4 trigl[NPHI];
    __shared__ float cstbuf[WCHUNK];

    const int tid  = threadIdx.x;
    const int bidx = (int)blockIdx.x;
    const int b    = (bidx >> 6) * 4;      // batches b .. b+3
    const int tile = bidx & 63;            // 8 x 8 tiles of 32x32
    const int i0 = (tile >> 3) * 32;
    const int j0 = (tile & 7) * 32;

    const float* trig = ws + 512;
    for (int idx = tid; idx < NPHI; idx += 256)
        trigl[idx] = *(const float4*)&trig[idx * 4];

    // compute-phase pixel mapping: wave = 16x16 px, lane = 2x2 px patch
    const int w  = tid >> 6;
    const int l  = tid & 63;
    const int wi = (w >> 1) * 16, wj = (w & 1) * 16;
    const int li = l >> 3, lj = l & 7;
    const int pi = i0 + wi + 2 * li;
    const int pj = j0 + wj + 2 * lj;
    const float xi = -1.f + ((float)pi + 0.5f) * DX_F;
    const float yj = -1.f + ((float)pj + 0.5f) * DX_F;

    // staging mapping: 16 threads per angle
    const int sa = tid >> 4;
    const int st = tid & 15;
    const float xlo = -1.f + ((float)i0 + 0.5f) * DX_F;
    const float xhi = xlo + 31.f * DX_F;
    const float ylo = -1.f + ((float)j0 + 0.5f) * DX_F;
    const float yhi = ylo + 31.f * DX_F;

    const float* fb0 = filt + (size_t)b * (NPHI * NT);

    float accL[4][2][2], accH[4][2][2];
    #pragma unroll
    for (int bb = 0; bb < 4; ++bb)
        #pragma unroll
        for (int di = 0; di < 2; ++di)
            #pragma unroll
            for (int dj = 0; dj < 2; ++dj) { accL[bb][di][dj] = 0.f; accH[bb][di][dj] = 0.f; }

    for (int p0 = 0; p0 < NPHI; p0 += WCHUNK) {
        __syncthreads();   // prev compute done (and trigl init on first iter)
        {
            const int p = p0 + sa;
            const float4 tg = trigl[p];
            const float umin = 256.5f + fminf(xlo * tg.x, xhi * tg.x)
                                      + fminf(ylo * tg.y, yhi * tg.y);
            const float b0f = floorf(umin) - 1.f;
            if (st == 0) cstbuf[sa] = 256.5f - b0f;
            const int base = (int)b0f + 5 * st - 1;
            #pragma unroll
            for (int pr = 0; pr < 2; ++pr) {
                const float* rA = fb0 + (size_t)(2 * pr) * (NPHI * NT) + (size_t)p * NT;
                const float* rB = rA + (size_t)(NPHI * NT);
                float fA[6], fB[6];
                #pragma unroll
                for (int k = 0; k < 6; ++k) {
                    int idx = base + k;
                    bool in = (unsigned)idx < 512u;
                    fA[k] = in ? rA[idx] : 0.f;
                    fB[k] = in ? rB[idx] : 0.f;
                }
                float4* wr = &win[sa][pr][5 * st];
                #pragma unroll
                for (int j = 0; j < 5; ++j)
                    wr[j] = make_float4(fA[j], fA[j + 1], fB[j], fB[j + 1]);
            }
        }
        __syncthreads();

        #pragma unroll 2
        for (int a = 0; a < WCHUNK; ++a) {
            const float4 tg = trigl[p0 + a];
            const float cst = cstbuf[a];
            const float4* wr0 = &win[a][0][0];
            const float u00 = xi * tg.x + yj * tg.y + cst;
            #pragma unroll
            for (int di = 0; di < 2; ++di) {
                float u = di ? (u00 + tg.z) : u00;
                #pragma unroll
                for (int dj = 0; dj < 2; ++dj) {
                    float fl  = floorf(u);
                    float wv  = u - fl;
                    float omw = 1.f - wv;
                    int   ip  = (int)fl;
                    float4 s01 = wr0[ip];
                    float4 s23 = wr0[ip + WSTR];
                    accL[0][di][dj] = fmaf(omw, s01.x, accL[0][di][dj]);
                    accH[0][di][dj] = fmaf(wv,  s01.y, accH[0][di][dj]);
                    accL[1][di][dj] = fmaf(omw, s01.z, accL[1][di][dj]);
                    accH[1][di][dj] = fmaf(wv,  s01.w, accH[1][di][dj]);
                    accL[2][di][dj] = fmaf(omw, s23.x, accL[2][di][dj]);
                    accH[2][di][dj] = fmaf(wv,  s23.y, accH[2][di][dj]);
                    accL[3][di][dj] = fmaf(omw, s23.z, accL[3][di][dj]);
                    accH[3][di][dj] = fmaf(wv,  s23.w, accH[3][di][dj]);
                    u += tg.w;
                }
            }
        }
    }

    #pragma unroll
    for (int bb = 0; bb < 4; ++bb) {
        float* ob = out + (size_t)(b + bb) * (NH * NH) + (size_t)pi * NH + pj;
        #pragma unroll
        for (int di = 0; di < 2; ++di) {
            float2 o = make_float2((accL[bb][di][0] + accH[bb][di][0]) * DPHI_F,
                                   (accL[bb][di][1] + accH[bb][di][1]) * DPHI_F);
            *(float2*)(ob + di * NH) = o;
        }
    }
}

// ---------------------------------------------------------------------------
extern "C" void kernel_launch(void* const* d_in, const int* in_sizes, int n_in,
                              void* d_out, int out_size, void* d_ws, size_t ws_size,
                              hipStream_t stream) {
    const float* sinos = (const float*)d_in[0];   // [32,720,512] f32
    const float* kern  = (const float*)d_in[1];   // [257] f32
    float* out = (float*)d_out;                   // [32,256,256] f32
    float* ws  = (float*)d_ws;

    float* filt = ws + 4096;   // 32*720*512 floats = 47.2 MB

    hipLaunchKernelGGL(build_tables_kernel, dim3(1), dim3(512), 0, stream, kern, ws);
    hipLaunchKernelGGL(conv_kernel, dim3((NB * NPHI) / 8), dim3(256), 0, stream,
                       sinos, ws, filt);
    hipLaunchKernelGGL(backproject_kernel, dim3((NB / 4) * 64), dim3(256), 0, stream,
                       filt, ws, out);
}

// Round 8
// 355.043 us; speedup vs baseline: 3.2397x; 1.1780x over previous
//
#include <hip/hip_runtime.h>
#include <hip/hip_bf16.h>

// Geometry constants
#define NPHI 720
#define NT   512
#define NH   256
#define NB   32

#define DPHI_F   0.004363323129985824f   // pi/720
#define INV_DT_F 181.01933598375618f     // 256/sqrt(2)
#define DX_F     0.0078125f              // 2/256
#define W2PI_F   0.012271846303085130f   // 2*pi/512

typedef __fp16  h2   __attribute__((ext_vector_type(2)));   // cvt_pkrtz return type
typedef _Float16 f16x2 __attribute__((ext_vector_type(2))); // fdot2 operand type

__device__ __forceinline__ float fdot2f(h2 a, float b_bits, float c) {
    return __builtin_amdgcn_fdot2(__builtin_bit_cast(f16x2, a),
                                  __builtin_bit_cast(f16x2, b_bits), c, false);
}

// ---------------------------------------------------------------------------
// Kernel A: build h = irfft(K, 512) (real even 512-tap) and the angle table.
// ws layout (floats): [0,512) h ; [512, 512+2880) trig {c/DT, s/DT, c*DX/DT, s*DX/DT}
// ---------------------------------------------------------------------------
__global__ void build_tables_kernel(const float* __restrict__ kern,
                                    float* __restrict__ ws) {
    __shared__ float ctab[512];
    __shared__ float kk[257];
    const int t = threadIdx.x;            // 512 threads
    if (t < 257) kk[t] = kern[t];
    ctab[t] = cosf((float)t * W2PI_F);
    __syncthreads();

    float acc = 0.f;
    for (int k = 1; k < 256; ++k)
        acc += kk[k] * ctab[(k * t) & 511];
    float h = (kk[0] + ((t & 1) ? -kk[256] : kk[256]) + 2.f * acc) * (1.f / 512.f);
    ws[t] = h;

    for (int p = t; p < NPHI; p += 512) {
        float ang = ((float)p + 0.5f) * DPHI_F;
        float s, c;
        sincosf(ang, &s, &c);
        float cd = c * INV_DT_F;
        float sd = s * INV_DT_F;
        ws[512 + 4 * p + 0] = cd;
        ws[512 + 4 * p + 1] = sd;
        ws[512 + 4 * p + 2] = cd * DX_F;
        ws[512 + 4 * p + 3] = sd * DX_F;
    }
}

// ---------------------------------------------------------------------------
// Kernel B: circular conv, transposed schedule (rows-as-lanes).
// ~at fp32 FMA roofline (~77 us ideal) -- leave alone.
// ---------------------------------------------------------------------------
#define CSTR 1044

#define LOAD16(dst, srcp) { \
    *(float4*)&(dst)[0]  = *(const float4*)&(srcp)[0];  \
    *(float4*)&(dst)[4]  = *(const float4*)&(srcp)[4];  \
    *(float4*)&(dst)[8]  = *(const float4*)&(srcp)[8];  \
    *(float4*)&(dst)[12] = *(const float4*)&(srcp)[12]; }

__global__ __launch_bounds__(256, 4) void conv_kernel(const float* __restrict__ g,
                                                      const float* __restrict__ hws,
                                                      float* __restrict__ filt) {
    __shared__ __attribute__((aligned(16))) float gld[8 * CSTR];
    __shared__ __attribute__((aligned(16))) float hls[512];
    const int tid = threadIdx.x;

    *(float2*)&hls[tid * 2] = *(const float2*)&hws[tid * 2];

    const long long rowbase = (long long)blockIdx.x * 8;
    const float4* gs = (const float4*)(g + rowbase * NT);
    #pragma unroll
    for (int k = 0; k < 4; ++k) {
        int q = tid + 256 * k;            // 0..1023
        int r = q >> 7, pos = q & 127;    // 128 float4 per row
        float4 v = gs[r * 128 + pos];
        *(float4*)&gld[r * CSTR + pos * 4]       = v;
        *(float4*)&gld[r * CSTR + 512 + pos * 4] = v;
    }
    __syncthreads();

    const int r  = tid & 7;
    const int c  = tid >> 3;        // 0..31
    const int o0 = c * 16;
    const float* row = &gld[r * CSTR];

    float acc[16];
    #pragma unroll
    for (int j = 0; j < 16; ++j) acc[j] = 0.f;

    float wA[16], wB[16], hh[16];
    LOAD16(wA, row + o0 + 496);
    LOAD16(wB, row + o0 + 512);

    #pragma unroll 1
    for (int m00 = 0; m00 < 512; m00 += 32) {
        LOAD16(hh, hls + m00);
        #pragma unroll
        for (int dm = 0; dm < 16; ++dm)
            #pragma unroll
            for (int j = 0; j < 16; ++j) {
                float x = (j >= dm) ? wB[j - dm] : wA[16 + j - dm];
                acc[j] = fmaf(hh[dm], x, acc[j]);
            }
        LOAD16(wB, row + o0 + 480 - m00);
        LOAD16(hh, hls + m00 + 16);
        #pragma unroll
        for (int dm = 0; dm < 16; ++dm)
            #pragma unroll
            for (int j = 0; j < 16; ++j) {
                float x = (j >= dm) ? wA[j - dm] : wB[16 + j - dm];
                acc[j] = fmaf(hh[dm], x, acc[j]);
            }
        if (m00 < 480) LOAD16(wA, row + o0 + 464 - m00);
    }

    float* dst = filt + (rowbase + r) * NT + o0;
    *(float4*)&dst[0]  = make_float4(acc[0],  acc[1],  acc[2],  acc[3]);
    *(float4*)&dst[4]  = make_float4(acc[4],  acc[5],  acc[6],  acc[7]);
    *(float4*)&dst[8]  = make_float4(acc[8],  acc[9],  acc[10], acc[11]);
    *(float4*)&dst[12] = make_float4(acc[12], acc[13], acc[14], acc[15]);
}

// ---------------------------------------------------------------------------
// Kernel C: backprojection v5 -- fp16 window + v_dot2_f32_f16.
// Grid = 8 batch-quads x 64 tiles (32x32 px) = 512 blocks (2/CU; LDS 21KB).
// Window slot s (16B) = {lo,hi}x4 batches in fp16:
//   lo = row[b0+s-1], hi = row[b0+s], b0 = floor(umin over tile corners)-1.
// One ds_read_b128 serves 4 samples; lerp = one v_dot2_f32_f16 per sample:
//   acc_b = fdot2((1-w, w), (lo_b, hi_b), acc_b)   [f32 accumulate].
// Index convention (R1/R3/R4-verified): ip = floor(q + cst), cst = 256.5-b0;
//   ip in [1,65] subset of [0,80).
// fp16 error budget: ~2.5e-4 RMS per tap -> ~3e-5 on output (threshold 9.7e-3).
// ---------------------------------------------------------------------------
#define WCHUNK 16
#define WSTR   82

__global__ __launch_bounds__(256, 2) void backproject_kernel(const float* __restrict__ filt,
                                                             const float* __restrict__ ws,
                                                             float* __restrict__ out) {
    __shared__ __attribute__((aligned(16))) float4 win[WCHUNK][WSTR];
    __shared__ float cstbuf[WCHUNK];

    const int tid  = threadIdx.x;
    const int bidx = (int)blockIdx.x;
    const int b    = (bidx >> 6) * 4;      // batches b .. b+3
    const int tile = bidx & 63;            // 8 x 8 tiles of 32x32
    const int i0 = (tile >> 3) * 32;
    const int j0 = (tile & 7) * 32;

    const float* trig = ws + 512;

    // compute-phase pixel mapping: wave = 16x16 px, lane = 2x2 px patch
    const int w  = tid >> 6;
    const int l  = tid & 63;
    const int wi = (w >> 1) * 16, wj = (w & 1) * 16;
    const int li = l >> 3, lj = l & 7;
    const int pi = i0 + wi + 2 * li;
    const int pj = j0 + wj + 2 * lj;
    const float xi = -1.f + ((float)pi + 0.5f) * DX_F;
    const float yj = -1.f + ((float)pj + 0.5f) * DX_F;

    // staging mapping: 16 threads per angle
    const int sa = tid >> 4;
    const int st = tid & 15;
    const float xlo = -1.f + ((float)i0 + 0.5f) * DX_F;
    const float xhi = xlo + 31.f * DX_F;
    const float ylo = -1.f + ((float)j0 + 0.5f) * DX_F;
    const float yhi = ylo + 31.f * DX_F;

    const float* fb0 = filt + (size_t)b * (NPHI * NT);

    float acc[4][2][2];
    #pragma unroll
    for (int bb = 0; bb < 4; ++bb)
        #pragma unroll
        for (int di = 0; di < 2; ++di)
            #pragma unroll
            for (int dj = 0; dj < 2; ++dj) acc[bb][di][dj] = 0.f;

    for (int p0 = 0; p0 < NPHI; p0 += WCHUNK) {
        __syncthreads();
        {
            const int p = p0 + sa;
            const float4 tg = *(const float4*)&trig[p * 4];
            const float umin = 256.5f + fminf(xlo * tg.x, xhi * tg.x)
                                      + fminf(ylo * tg.y, yhi * tg.y);
            const float b0f = floorf(umin) - 1.f;
            if (st == 0) cstbuf[sa] = 256.5f - b0f;
            const int base = (int)b0f + 5 * st - 1;
            float f[4][6];
            #pragma unroll
            for (int bb = 0; bb < 4; ++bb) {
                const float* rr = fb0 + (size_t)bb * (NPHI * NT) + (size_t)p * NT;
                #pragma unroll
                for (int k = 0; k < 6; ++k) {
                    int idx = base + k;
                    f[bb][k] = ((unsigned)idx < 512u) ? rr[idx] : 0.f;
                }
            }
            float4* wr = &win[sa][5 * st];
            #pragma unroll
            for (int j = 0; j < 5; ++j) {
                h2 a0 = __builtin_amdgcn_cvt_pkrtz(f[0][j], f[0][j + 1]);
                h2 a1 = __builtin_amdgcn_cvt_pkrtz(f[1][j], f[1][j + 1]);
                h2 a2 = __builtin_amdgcn_cvt_pkrtz(f[2][j], f[2][j + 1]);
                h2 a3 = __builtin_amdgcn_cvt_pkrtz(f[3][j], f[3][j + 1]);
                wr[j] = make_float4(__builtin_bit_cast(float, a0),
                                    __builtin_bit_cast(float, a1),
                                    __builtin_bit_cast(float, a2),
                                    __builtin_bit_cast(float, a3));
            }
        }
        __syncthreads();

        #pragma unroll 2
        for (int a = 0; a < WCHUNK; ++a) {
            const float4 tg = *(const float4*)&trig[(p0 + a) * 4]; // cd,sd,dci,dsj
            const float cst = cstbuf[a];
            const float4* wr = &win[a][0];
            const float u00 = xi * tg.x + yj * tg.y + cst;
            #pragma unroll
            for (int di = 0; di < 2; ++di) {
                float u = di ? (u00 + tg.z) : u00;
                #pragma unroll
                for (int dj = 0; dj < 2; ++dj) {
                    float fl = floorf(u);
                    float wv = u - fl;
                    int  ip  = (int)fl;
                    h2   wp  = __builtin_amdgcn_cvt_pkrtz(1.f - wv, wv);
                    float4 s = wr[ip];
                    acc[0][di][dj] = fdot2f(wp, s.x, acc[0][di][dj]);
                    acc[1][di][dj] = fdot2f(wp, s.y, acc[1][di][dj]);
                    acc[2][di][dj] = fdot2f(wp, s.z, acc[2][di][dj]);
                    acc[3][di][dj] = fdot2f(wp, s.w, acc[3][di][dj]);
                    u += tg.w;
                }
            }
        }
    }

    #pragma unroll
    for (int bb = 0; bb < 4; ++bb) {
        float* ob = out + (size_t)(b + bb) * (NH * NH) + (size_t)pi * NH + pj;
        #pragma unroll
        for (int di = 0; di < 2; ++di) {
            float2 o = make_float2(acc[bb][di][0] * DPHI_F,
                                   acc[bb][di][1] * DPHI_F);
            *(float2*)(ob + di * NH) = o;
        }
    }
}

// ---------------------------------------------------------------------------
extern "C" void kernel_launch(void* const* d_in, const int* in_sizes, int n_in,
                              void* d_out, int out_size, void* d_ws, size_t ws_size,
                              hipStream_t stream) {
    const float* sinos = (const float*)d_in[0];   // [32,720,512] f32
    const float* kern  = (const float*)d_in[1];   // [257] f32
    float* out = (float*)d_out;                   // [32,256,256] f32
    float* ws  = (float*)d_ws;

    float* filt = ws + 4096;   // 32*720*512 floats = 47.2 MB

    hipLaunchKernelGGL(build_tables_kernel, dim3(1), dim3(512), 0, stream, kern, ws);
    hipLaunchKernelGGL(conv_kernel, dim3((NB * NPHI) / 8), dim3(256), 0, stream,
                       sinos, ws, filt);
    hipLaunchKernelGGL(backproject_kernel, dim3((NB / 4) * 64), dim3(256), 0, stream,
                       filt, ws, out);
}

// Round 9
// 317.405 us; speedup vs baseline: 3.6239x; 1.1186x over previous
//
#include <hip/hip_runtime.h>
#include <hip/hip_bf16.h>

// Geometry constants
#define NPHI 720
#define NT   512
#define NH   256
#define NB   32

#define DPHI_F   0.004363323129985824f   // pi/720
#define INV_DT_F 181.01933598375618f     // 256/sqrt(2)
#define DX_F     0.0078125f              // 2/256
#define W2PI_F   0.012271846303085130f   // 2*pi/512

typedef __fp16  h2   __attribute__((ext_vector_type(2)));   // cvt_pkrtz return type
typedef _Float16 f16x2 __attribute__((ext_vector_type(2))); // fdot2 operand type

__device__ __forceinline__ float fdot2f(h2 a, float b_bits, float c) {
    return __builtin_amdgcn_fdot2(__builtin_bit_cast(f16x2, a),
                                  __builtin_bit_cast(f16x2, b_bits), c, false);
}

// ---------------------------------------------------------------------------
// Kernel A: build h = irfft(K, 512) (real even 512-tap) and the angle table.
// ws layout (floats): [0,512) h ; [512, 512+2880) trig {c/DT, s/DT, c*DX/DT, s*DX/DT}
// ---------------------------------------------------------------------------
__global__ void build_tables_kernel(const float* __restrict__ kern,
                                    float* __restrict__ ws) {
    __shared__ float ctab[512];
    __shared__ float kk[257];
    const int t = threadIdx.x;            // 512 threads
    if (t < 257) kk[t] = kern[t];
    ctab[t] = cosf((float)t * W2PI_F);
    __syncthreads();

    float acc = 0.f;
    for (int k = 1; k < 256; ++k)
        acc += kk[k] * ctab[(k * t) & 511];
    float h = (kk[0] + ((t & 1) ? -kk[256] : kk[256]) + 2.f * acc) * (1.f / 512.f);
    ws[t] = h;

    for (int p = t; p < NPHI; p += 512) {
        float ang = ((float)p + 0.5f) * DPHI_F;
        float s, c;
        sincosf(ang, &s, &c);
        float cd = c * INV_DT_F;
        float sd = s * INV_DT_F;
        ws[512 + 4 * p + 0] = cd;
        ws[512 + 4 * p + 1] = sd;
        ws[512 + 4 * p + 2] = cd * DX_F;
        ws[512 + 4 * p + 3] = sd * DX_F;
    }
}

// ---------------------------------------------------------------------------
// Kernel B: circular conv, transposed schedule (rows-as-lanes).
// ~at fp32 FMA roofline (~77 us ideal) -- leave alone.
// ---------------------------------------------------------------------------
#define CSTR 1044

#define LOAD16(dst, srcp) { \
    *(float4*)&(dst)[0]  = *(const float4*)&(srcp)[0];  \
    *(float4*)&(dst)[4]  = *(const float4*)&(srcp)[4];  \
    *(float4*)&(dst)[8]  = *(const float4*)&(srcp)[8];  \
    *(float4*)&(dst)[12] = *(const float4*)&(srcp)[12]; }

__global__ __launch_bounds__(256, 4) void conv_kernel(const float* __restrict__ g,
                                                      const float* __restrict__ hws,
                                                      float* __restrict__ filt) {
    __shared__ __attribute__((aligned(16))) float gld[8 * CSTR];
    __shared__ __attribute__((aligned(16))) float hls[512];
    const int tid = threadIdx.x;

    *(float2*)&hls[tid * 2] = *(const float2*)&hws[tid * 2];

    const long long rowbase = (long long)blockIdx.x * 8;
    const float4* gs = (const float4*)(g + rowbase * NT);
    #pragma unroll
    for (int k = 0; k < 4; ++k) {
        int q = tid + 256 * k;            // 0..1023
        int r = q >> 7, pos = q & 127;    // 128 float4 per row
        float4 v = gs[r * 128 + pos];
        *(float4*)&gld[r * CSTR + pos * 4]       = v;
        *(float4*)&gld[r * CSTR + 512 + pos * 4] = v;
    }
    __syncthreads();

    const int r  = tid & 7;
    const int c  = tid >> 3;        // 0..31
    const int o0 = c * 16;
    const float* row = &gld[r * CSTR];

    float acc[16];
    #pragma unroll
    for (int j = 0; j < 16; ++j) acc[j] = 0.f;

    float wA[16], wB[16], hh[16];
    LOAD16(wA, row + o0 + 496);
    LOAD16(wB, row + o0 + 512);

    #pragma unroll 1
    for (int m00 = 0; m00 < 512; m00 += 32) {
        LOAD16(hh, hls + m00);
        #pragma unroll
        for (int dm = 0; dm < 16; ++dm)
            #pragma unroll
            for (int j = 0; j < 16; ++j) {
                float x = (j >= dm) ? wB[j - dm] : wA[16 + j - dm];
                acc[j] = fmaf(hh[dm], x, acc[j]);
            }
        LOAD16(wB, row + o0 + 480 - m00);
        LOAD16(hh, hls + m00 + 16);
        #pragma unroll
        for (int dm = 0; dm < 16; ++dm)
            #pragma unroll
            for (int j = 0; j < 16; ++j) {
                float x = (j >= dm) ? wA[j - dm] : wB[16 + j - dm];
                acc[j] = fmaf(hh[dm], x, acc[j]);
            }
        if (m00 < 480) LOAD16(wA, row + o0 + 464 - m00);
    }

    float* dst = filt + (rowbase + r) * NT + o0;
    *(float4*)&dst[0]  = make_float4(acc[0],  acc[1],  acc[2],  acc[3]);
    *(float4*)&dst[4]  = make_float4(acc[4],  acc[5],  acc[6],  acc[7]);
    *(float4*)&dst[8]  = make_float4(acc[8],  acc[9],  acc[10], acc[11]);
    *(float4*)&dst[12] = make_float4(acc[12], acc[13], acc[14], acc[15]);
}

// ---------------------------------------------------------------------------
// Kernel C: backprojection v6 -- fp16 window + fdot2, 2-way angle split.
// Grid = 2 halves x 8 batch-quads x 64 tiles = 1024 blocks (4/CU; LDS 20KB;
// 16 waves/CU). Each block handles 360 angles; halves combine via
// unsafeAtomicAdd (global_atomic_add_f32) onto memset-zeroed out.
// Exactly 2 commutative f32 addends per pixel -> bit-deterministic.
// Window slot s (16B) = {lo,hi}x4 batches in fp16:
//   lo = row[b0+s-1], hi = row[b0+s], b0 = floor(umin over tile corners)-1.
// One ds_read_b128 serves 4 samples; lerp = one v_dot2_f32_f16 per sample.
// Index convention (R1/R3/R4-verified): ip = floor(q + cst), cst = 256.5-b0.
// WCHUNK=15 divides 360; staging uses 15x16=240 of 256 threads.
// ---------------------------------------------------------------------------
#define WCHUNK 15
#define WSTR   82

__global__ __launch_bounds__(256, 4) void backproject_kernel(const float* __restrict__ filt,
                                                             const float* __restrict__ ws,
                                                             float* __restrict__ out) {
    __shared__ __attribute__((aligned(16))) float4 win[WCHUNK][WSTR];
    __shared__ float cstbuf[WCHUNK];

    const int tid  = threadIdx.x;
    const int bidx = (int)blockIdx.x;
    const int half = bidx >> 9;            // 0 or 1: angle range
    const int rem  = bidx & 511;
    const int b    = (rem >> 6) * 4;       // batches b .. b+3
    const int tile = rem & 63;             // 8 x 8 tiles of 32x32
    const int i0 = (tile >> 3) * 32;
    const int j0 = (tile & 7) * 32;

    const float* trig = ws + 512;

    // compute-phase pixel mapping: wave = 16x16 px, lane = 2x2 px patch
    const int w  = tid >> 6;
    const int l  = tid & 63;
    const int wi = (w >> 1) * 16, wj = (w & 1) * 16;
    const int li = l >> 3, lj = l & 7;
    const int pi = i0 + wi + 2 * li;
    const int pj = j0 + wj + 2 * lj;
    const float xi = -1.f + ((float)pi + 0.5f) * DX_F;
    const float yj = -1.f + ((float)pj + 0.5f) * DX_F;

    // staging mapping: 16 threads per angle, angles sa in [0,15)
    const int sa = tid >> 4;
    const int st = tid & 15;
    const float xlo = -1.f + ((float)i0 + 0.5f) * DX_F;
    const float xhi = xlo + 31.f * DX_F;
    const float ylo = -1.f + ((float)j0 + 0.5f) * DX_F;
    const float yhi = ylo + 31.f * DX_F;

    const float* fb0 = filt + (size_t)b * (NPHI * NT);

    float acc[4][2][2];
    #pragma unroll
    for (int bb = 0; bb < 4; ++bb)
        #pragma unroll
        for (int di = 0; di < 2; ++di)
            #pragma unroll
            for (int dj = 0; dj < 2; ++dj) acc[bb][di][dj] = 0.f;

    const int pbeg = half * 360;
    for (int p0 = pbeg; p0 < pbeg + 360; p0 += WCHUNK) {
        __syncthreads();
        if (sa < WCHUNK) {
            const int p = p0 + sa;
            const float4 tg = *(const float4*)&trig[p * 4];
            const float umin = 256.5f + fminf(xlo * tg.x, xhi * tg.x)
                                      + fminf(ylo * tg.y, yhi * tg.y);
            const float b0f = floorf(umin) - 1.f;
            if (st == 0) cstbuf[sa] = 256.5f - b0f;
            const int base = (int)b0f + 5 * st - 1;
            float f[4][6];
            #pragma unroll
            for (int bb = 0; bb < 4; ++bb) {
                const float* rr = fb0 + (size_t)bb * (NPHI * NT) + (size_t)p * NT;
                #pragma unroll
                for (int k = 0; k < 6; ++k) {
                    int idx = base + k;
                    f[bb][k] = ((unsigned)idx < 512u) ? rr[idx] : 0.f;
                }
            }
            float4* wr = &win[sa][5 * st];
            #pragma unroll
            for (int j = 0; j < 5; ++j) {
                h2 a0 = __builtin_amdgcn_cvt_pkrtz(f[0][j], f[0][j + 1]);
                h2 a1 = __builtin_amdgcn_cvt_pkrtz(f[1][j], f[1][j + 1]);
                h2 a2 = __builtin_amdgcn_cvt_pkrtz(f[2][j], f[2][j + 1]);
                h2 a3 = __builtin_amdgcn_cvt_pkrtz(f[3][j], f[3][j + 1]);
                wr[j] = make_float4(__builtin_bit_cast(float, a0),
                                    __builtin_bit_cast(float, a1),
                                    __builtin_bit_cast(float, a2),
                                    __builtin_bit_cast(float, a3));
            }
        }
        __syncthreads();

        #pragma unroll 3
        for (int a = 0; a < WCHUNK; ++a) {
            const float4 tg = *(const float4*)&trig[(p0 + a) * 4]; // cd,sd,dci,dsj
            const float cst = cstbuf[a];
            const float4* wr = &win[a][0];
            const float u00 = xi * tg.x + yj * tg.y + cst;
            #pragma unroll
            for (int di = 0; di < 2; ++di) {
                float u = di ? (u00 + tg.z) : u00;
                #pragma unroll
                for (int dj = 0; dj < 2; ++dj) {
                    float fl = floorf(u);
                    float wv = u - fl;
                    int  ip  = (int)fl;
                    h2   wp  = __builtin_amdgcn_cvt_pkrtz(1.f - wv, wv);
                    float4 s = wr[ip];
                    acc[0][di][dj] = fdot2f(wp, s.x, acc[0][di][dj]);
                    acc[1][di][dj] = fdot2f(wp, s.y, acc[1][di][dj]);
                    acc[2][di][dj] = fdot2f(wp, s.z, acc[2][di][dj]);
                    acc[3][di][dj] = fdot2f(wp, s.w, acc[3][di][dj]);
                    u += tg.w;
                }
            }
        }
    }

    #pragma unroll
    for (int bb = 0; bb < 4; ++bb) {
        float* ob = out + (size_t)(b + bb) * (NH * NH) + (size_t)pi * NH + pj;
        #pragma unroll
        for (int di = 0; di < 2; ++di)
            #pragma unroll
            for (int dj = 0; dj < 2; ++dj)
                unsafeAtomicAdd(ob + di * NH + dj, acc[bb][di][dj] * DPHI_F);
    }
}

// ---------------------------------------------------------------------------
extern "C" void kernel_launch(void* const* d_in, const int* in_sizes, int n_in,
                              void* d_out, int out_size, void* d_ws, size_t ws_size,
                              hipStream_t stream) {
    const float* sinos = (const float*)d_in[0];   // [32,720,512] f32
    const float* kern  = (const float*)d_in[1];   // [257] f32
    float* out = (float*)d_out;                   // [32,256,256] f32
    float* ws  = (float*)d_ws;

    float* filt = ws + 4096;   // 32*720*512 floats = 47.2 MB

    hipMemsetAsync(d_out, 0, (size_t)out_size * sizeof(float), stream);
    hipLaunchKernelGGL(build_tables_kernel, dim3(1), dim3(512), 0, stream, kern, ws);
    hipLaunchKernelGGL(conv_kernel, dim3((NB * NPHI) / 8), dim3(256), 0, stream,
                       sinos, ws, filt);
    hipLaunchKernelGGL(backproject_kernel, dim3(2 * (NB / 4) * 64), dim3(256), 0, stream,
                       filt, ws, out);
}

// Round 10
// 314.020 us; speedup vs baseline: 3.6630x; 1.0108x over previous
//
#include <hip/hip_runtime.h>
#include <hip/hip_bf16.h>

// Geometry constants
#define NPHI 720
#define NT   512
#define NH   256
#define NB   32

#define DPHI_F   0.004363323129985824f   // pi/720
#define INV_DT_F 181.01933598375618f     // 256/sqrt(2)
#define DX_F     0.0078125f              // 2/256
#define W2PI_F   0.012271846303085130f   // 2*pi/512

typedef __fp16  h2   __attribute__((ext_vector_type(2)));   // cvt_pkrtz return type
typedef _Float16 f16x2 __attribute__((ext_vector_type(2))); // fdot2 operand type

__device__ __forceinline__ float fdot2f(h2 a, float b_bits, float c) {
    return __builtin_amdgcn_fdot2(__builtin_bit_cast(f16x2, a),
                                  __builtin_bit_cast(f16x2, b_bits), c, false);
}

// ---------------------------------------------------------------------------
// Kernel A: build h = irfft(K, 512) (real even 512-tap) and the angle table.
// ws layout (floats): [0,512) h ; [512, 512+2880) trig {c/DT, s/DT, c*DX/DT, s*DX/DT}
// ---------------------------------------------------------------------------
__global__ void build_tables_kernel(const float* __restrict__ kern,
                                    float* __restrict__ ws) {
    __shared__ float ctab[512];
    __shared__ float kk[257];
    const int t = threadIdx.x;            // 512 threads
    if (t < 257) kk[t] = kern[t];
    ctab[t] = cosf((float)t * W2PI_F);
    __syncthreads();

    float acc = 0.f;
    for (int k = 1; k < 256; ++k)
        acc += kk[k] * ctab[(k * t) & 511];
    float h = (kk[0] + ((t & 1) ? -kk[256] : kk[256]) + 2.f * acc) * (1.f / 512.f);
    ws[t] = h;

    for (int p = t; p < NPHI; p += 512) {
        float ang = ((float)p + 0.5f) * DPHI_F;
        float s, c;
        sincosf(ang, &s, &c);
        float cd = c * INV_DT_F;
        float sd = s * INV_DT_F;
        ws[512 + 4 * p + 0] = cd;
        ws[512 + 4 * p + 1] = sd;
        ws[512 + 4 * p + 2] = cd * DX_F;
        ws[512 + 4 * p + 3] = sd * DX_F;
    }
}

// ---------------------------------------------------------------------------
// Kernel B: circular conv, transposed schedule (rows-as-lanes).
// ~at fp32 FMA roofline (~77 us ideal) -- leave alone.
// ---------------------------------------------------------------------------
#define CSTR 1044

#define LOAD16(dst, srcp) { \
    *(float4*)&(dst)[0]  = *(const float4*)&(srcp)[0];  \
    *(float4*)&(dst)[4]  = *(const float4*)&(srcp)[4];  \
    *(float4*)&(dst)[8]  = *(const float4*)&(srcp)[8];  \
    *(float4*)&(dst)[12] = *(const float4*)&(srcp)[12]; }

__global__ __launch_bounds__(256, 4) void conv_kernel(const float* __restrict__ g,
                                                      const float* __restrict__ hws,
                                                      float* __restrict__ filt) {
    __shared__ __attribute__((aligned(16))) float gld[8 * CSTR];
    __shared__ __attribute__((aligned(16))) float hls[512];
    const int tid = threadIdx.x;

    *(float2*)&hls[tid * 2] = *(const float2*)&hws[tid * 2];

    const long long rowbase = (long long)blockIdx.x * 8;
    const float4* gs = (const float4*)(g + rowbase * NT);
    #pragma unroll
    for (int k = 0; k < 4; ++k) {
        int q = tid + 256 * k;            // 0..1023
        int r = q >> 7, pos = q & 127;    // 128 float4 per row
        float4 v = gs[r * 128 + pos];
        *(float4*)&gld[r * CSTR + pos * 4]       = v;
        *(float4*)&gld[r * CSTR + 512 + pos * 4] = v;
    }
    __syncthreads();

    const int r  = tid & 7;
    const int c  = tid >> 3;        // 0..31
    const int o0 = c * 16;
    const float* row = &gld[r * CSTR];

    float acc[16];
    #pragma unroll
    for (int j = 0; j < 16; ++j) acc[j] = 0.f;

    float wA[16], wB[16], hh[16];
    LOAD16(wA, row + o0 + 496);
    LOAD16(wB, row + o0 + 512);

    #pragma unroll 1
    for (int m00 = 0; m00 < 512; m00 += 32) {
        LOAD16(hh, hls + m00);
        #pragma unroll
        for (int dm = 0; dm < 16; ++dm)
            #pragma unroll
            for (int j = 0; j < 16; ++j) {
                float x = (j >= dm) ? wB[j - dm] : wA[16 + j - dm];
                acc[j] = fmaf(hh[dm], x, acc[j]);
            }
        LOAD16(wB, row + o0 + 480 - m00);
        LOAD16(hh, hls + m00 + 16);
        #pragma unroll
        for (int dm = 0; dm < 16; ++dm)
            #pragma unroll
            for (int j = 0; j < 16; ++j) {
                float x = (j >= dm) ? wA[j - dm] : wB[16 + j - dm];
                acc[j] = fmaf(hh[dm], x, acc[j]);
            }
        if (m00 < 480) LOAD16(wA, row + o0 + 464 - m00);
    }

    float* dst = filt + (rowbase + r) * NT + o0;
    *(float4*)&dst[0]  = make_float4(acc[0],  acc[1],  acc[2],  acc[3]);
    *(float4*)&dst[4]  = make_float4(acc[4],  acc[5],  acc[6],  acc[7]);
    *(float4*)&dst[8]  = make_float4(acc[8],  acc[9],  acc[10], acc[11]);
    *(float4*)&dst[12] = make_float4(acc[12], acc[13], acc[14], acc[15]);
}

// ---------------------------------------------------------------------------
// Kernel C: backprojection v7 -- fp16 window + fdot2, 4-way angle split.
// Grid = 4 quarters x 8 batch-quads x 64 tiles = 2048 blocks (8/CU; LDS
// 19.97KB x 8 = 159.7KB -- exact fit; 32 waves/CU). Each block handles 180
// angles (12 chunks of 15); quarters combine via unsafeAtomicAdd onto
// memset-zeroed out (4 commutative f32 addends, order jitter ~2e-8).
// Window slot s (16B) = {lo,hi}x4 batches in fp16:
//   lo = row[b0+s-1], hi = row[b0+s], b0 = floor(umin over tile corners)-1.
// One ds_read_b128 serves 4 samples; lerp = one v_dot2_f32_f16 per sample.
// Index convention (R1/R3/R4-verified): ip = floor(q + cst), cst = 256.5-b0.
// ---------------------------------------------------------------------------
#define WCHUNK 15
#define WSTR   82

__global__ __launch_bounds__(256, 8) void backproject_kernel(const float* __restrict__ filt,
                                                             const float* __restrict__ ws,
                                                             float* __restrict__ out) {
    __shared__ __attribute__((aligned(16))) float4 win[WCHUNK][WSTR];
    __shared__ float cstbuf[WCHUNK];

    const int tid  = threadIdx.x;
    const int bidx = (int)blockIdx.x;
    const int quarter = bidx >> 9;         // 0..3: angle range
    const int rem  = bidx & 511;
    const int b    = (rem >> 6) * 4;       // batches b .. b+3
    const int tile = rem & 63;             // 8 x 8 tiles of 32x32
    const int i0 = (tile >> 3) * 32;
    const int j0 = (tile & 7) * 32;

    const float* trig = ws + 512;

    // compute-phase pixel mapping: wave = 16x16 px, lane = 2x2 px patch
    const int w  = tid >> 6;
    const int l  = tid & 63;
    const int wi = (w >> 1) * 16, wj = (w & 1) * 16;
    const int li = l >> 3, lj = l & 7;
    const int pi = i0 + wi + 2 * li;
    const int pj = j0 + wj + 2 * lj;
    const float xi = -1.f + ((float)pi + 0.5f) * DX_F;
    const float yj = -1.f + ((float)pj + 0.5f) * DX_F;

    // staging mapping: 16 threads per angle, angles sa in [0,15)
    const int sa = tid >> 4;
    const int st = tid & 15;
    const float xlo = -1.f + ((float)i0 + 0.5f) * DX_F;
    const float xhi = xlo + 31.f * DX_F;
    const float ylo = -1.f + ((float)j0 + 0.5f) * DX_F;
    const float yhi = ylo + 31.f * DX_F;

    const float* fb0 = filt + (size_t)b * (NPHI * NT);

    float acc[4][2][2];
    #pragma unroll
    for (int bb = 0; bb < 4; ++bb)
        #pragma unroll
        for (int di = 0; di < 2; ++di)
            #pragma unroll
            for (int dj = 0; dj < 2; ++dj) acc[bb][di][dj] = 0.f;

    const int pbeg = quarter * 180;
    for (int p0 = pbeg; p0 < pbeg + 180; p0 += WCHUNK) {
        __syncthreads();
        if (sa < WCHUNK) {
            const int p = p0 + sa;
            const float4 tg = *(const float4*)&trig[p * 4];
            const float umin = 256.5f + fminf(xlo * tg.x, xhi * tg.x)
                                      + fminf(ylo * tg.y, yhi * tg.y);
            const float b0f = floorf(umin) - 1.f;
            if (st == 0) cstbuf[sa] = 256.5f - b0f;
            const int base = (int)b0f + 5 * st - 1;
            float f[4][6];
            #pragma unroll
            for (int bb = 0; bb < 4; ++bb) {
                const float* rr = fb0 + (size_t)bb * (NPHI * NT) + (size_t)p * NT;
                #pragma unroll
                for (int k = 0; k < 6; ++k) {
                    int idx = base + k;
                    f[bb][k] = ((unsigned)idx < 512u) ? rr[idx] : 0.f;
                }
            }
            float4* wr = &win[sa][5 * st];
            #pragma unroll
            for (int j = 0; j < 5; ++j) {
                h2 a0 = __builtin_amdgcn_cvt_pkrtz(f[0][j], f[0][j + 1]);
                h2 a1 = __builtin_amdgcn_cvt_pkrtz(f[1][j], f[1][j + 1]);
                h2 a2 = __builtin_amdgcn_cvt_pkrtz(f[2][j], f[2][j + 1]);
                h2 a3 = __builtin_amdgcn_cvt_pkrtz(f[3][j], f[3][j + 1]);
                wr[j] = make_float4(__builtin_bit_cast(float, a0),
                                    __builtin_bit_cast(float, a1),
                                    __builtin_bit_cast(float, a2),
                                    __builtin_bit_cast(float, a3));
            }
        }
        __syncthreads();

        #pragma unroll 3
        for (int a = 0; a < WCHUNK; ++a) {
            const float4 tg = *(const float4*)&trig[(p0 + a) * 4]; // cd,sd,dci,dsj
            const float cst = cstbuf[a];
            const float4* wr = &win[a][0];
            const float u00 = xi * tg.x + yj * tg.y + cst;
            #pragma unroll
            for (int di = 0; di < 2; ++di) {
                float u = di ? (u00 + tg.z) : u00;
                #pragma unroll
                for (int dj = 0; dj < 2; ++dj) {
                    float fl = floorf(u);
                    float wv = u - fl;
                    int  ip  = (int)fl;
                    h2   wp  = __builtin_amdgcn_cvt_pkrtz(1.f - wv, wv);
                    float4 s = wr[ip];
                    acc[0][di][dj] = fdot2f(wp, s.x, acc[0][di][dj]);
                    acc[1][di][dj] = fdot2f(wp, s.y, acc[1][di][dj]);
                    acc[2][di][dj] = fdot2f(wp, s.z, acc[2][di][dj]);
                    acc[3][di][dj] = fdot2f(wp, s.w, acc[3][di][dj]);
                    u += tg.w;
                }
            }
        }
    }

    #pragma unroll
    for (int bb = 0; bb < 4; ++bb) {
        float* ob = out + (size_t)(b + bb) * (NH * NH) + (size_t)pi * NH + pj;
        #pragma unroll
        for (int di = 0; di < 2; ++di)
            #pragma unroll
            for (int dj = 0; dj < 2; ++dj)
                unsafeAtomicAdd(ob + di * NH + dj, acc[bb][di][dj] * DPHI_F);
    }
}

// ---------------------------------------------------------------------------
extern "C" void kernel_launch(void* const* d_in, const int* in_sizes, int n_in,
                              void* d_out, int out_size, void* d_ws, size_t ws_size,
                              hipStream_t stream) {
    const float* sinos = (const float*)d_in[0];   // [32,720,512] f32
    const float* kern  = (const float*)d_in[1];   // [257] f32
    float* out = (float*)d_out;                   // [32,256,256] f32
    float* ws  = (float*)d_ws;

    float* filt = ws + 4096;   // 32*720*512 floats = 47.2 MB

    hipMemsetAsync(d_out, 0, (size_t)out_size * sizeof(float), stream);
    hipLaunchKernelGGL(build_tables_kernel, dim3(1), dim3(512), 0, stream, kern, ws);
    hipLaunchKernelGGL(conv_kernel, dim3((NB * NPHI) / 8), dim3(256), 0, stream,
                       sinos, ws, filt);
    hipLaunchKernelGGL(backproject_kernel, dim3(4 * (NB / 4) * 64), dim3(256), 0, stream,
                       filt, ws, out);
}

// Round 11
// 248.845 us; speedup vs baseline: 4.6223x; 1.2619x over previous
//
#include <hip/hip_runtime.h>
#include <hip/hip_bf16.h>

// Geometry constants
#define NPHI 720
#define NT   512
#define NH   256
#define NB   32

#define DPHI_F   0.004363323129985824f   // pi/720
#define INV_DT_F 181.01933598375618f     // 256/sqrt(2)
#define DX_F     0.0078125f              // 2/256
#define W2PI_F   0.012271846303085130f   // 2*pi/512

typedef __fp16  h2   __attribute__((ext_vector_type(2)));   // cvt_pkrtz return type
typedef _Float16 f16x2 __attribute__((ext_vector_type(2))); // fdot2 operand type
typedef _Float16 f16x8 __attribute__((ext_vector_type(8))); // mfma A/B operand
typedef float    f32x4 __attribute__((ext_vector_type(4))); // mfma C/D

__device__ __forceinline__ float fdot2f(h2 a, float b_bits, float c) {
    return __builtin_amdgcn_fdot2(__builtin_bit_cast(f16x2, a),
                                  __builtin_bit_cast(f16x2, b_bits), c, false);
}
__device__ __forceinline__ unsigned short f2h(float x) {
    h2 p = __builtin_amdgcn_cvt_pkrtz(x, x);
    return __builtin_bit_cast(ushort2, p).x;
}

// ---------------------------------------------------------------------------
// Kernel A: build h = irfft(K,512), trig table, and circulant Ht (fp16).
// ws floats: [0,512) h ; [512,3392) trig {c/DT,s/DT,c*DX/DT,s*DX/DT}
// ws+4096: Ht[512][512] fp16, Ht[o][m] = h[(o-m)&511]  (the GEMM B, pre-
//          transposed so B-staging reads rows coalesced).
// ---------------------------------------------------------------------------
__global__ void build_tables_kernel(const float* __restrict__ kern,
                                    float* __restrict__ ws) {
    __shared__ float ctab[512];
    __shared__ float kk[257];
    __shared__ unsigned short hh[512];
    const int t = threadIdx.x;            // 512 threads
    if (t < 257) kk[t] = kern[t];
    ctab[t] = cosf((float)t * W2PI_F);
    __syncthreads();

    float acc = 0.f;
    for (int k = 1; k < 256; ++k)
        acc += kk[k] * ctab[(k * t) & 511];
    float h = (kk[0] + ((t & 1) ? -kk[256] : kk[256]) + 2.f * acc) * (1.f / 512.f);
    ws[t] = h;
    hh[t] = f2h(h);

    for (int p = t; p < NPHI; p += 512) {
        float ang = ((float)p + 0.5f) * DPHI_F;
        float s, c;
        sincosf(ang, &s, &c);
        float cd = c * INV_DT_F;
        float sd = s * INV_DT_F;
        ws[512 + 4 * p + 0] = cd;
        ws[512 + 4 * p + 1] = sd;
        ws[512 + 4 * p + 2] = cd * DX_F;
        ws[512 + 4 * p + 3] = sd * DX_F;
    }
    __syncthreads();

    // Ht row o = t: pack pairs (m, m+1)
    unsigned int* dst = (unsigned int*)((unsigned short*)(ws + 4096) + (size_t)t * NT);
    for (int mp = 0; mp < 256; ++mp) {
        unsigned int lo = hh[(t - 2 * mp) & 511];
        unsigned int hi = hh[(t - 2 * mp - 1) & 511];
        dst[mp] = lo | (hi << 16);
    }
}

// ---------------------------------------------------------------------------
// Kernel B: filtering as GEMM on matrix cores.
// filt[r][o] = sum_m g[r][m] * h[(o-m)&511]  ==  G[23040x512] @ H[512x512],
// H[k][o] = Ht[o][k].  Tile 64(M) x 256(N) x 32(K); 4 waves, wave=32x128
// (2x8 frags of 16x16); 720 blocks = (23040/64) x (512/256).
// LDS strides 40 fp16 (80B): 16B-aligned b128 ops, 20-bank row step -> 2-way
// (free).  A staged f32->fp16 via cvt_pkrtz; B copied from Ht rows.
// mfma_f32_16x16x32_f16 layouts (m89-verified D; A/B share k-map so the
// k-permutation cancels): a: A[l&15][(l>>4)*8+e], b: B[(l>>4)*8+e][l&15],
// d reg v: D[(l>>4)*4+v][l&15].
// Output written as fp16 (bit-identical to what BP staging formerly made).
// ---------------------------------------------------------------------------
#define ASTR 40
#define BSTR 40

__global__ __launch_bounds__(256) void conv_gemm_kernel(const float* __restrict__ g,
                                                        const unsigned short* __restrict__ Ht,
                                                        unsigned short* __restrict__ filt) {
    __shared__ __attribute__((aligned(16))) unsigned short As[64 * ASTR];
    __shared__ __attribute__((aligned(16))) unsigned short Bs[256 * BSTR];
    const int tid = threadIdx.x;
    const int m0 = ((int)blockIdx.x >> 1) * 64;
    const int n0 = ((int)blockIdx.x & 1) * 256;

    const int w = tid >> 6, l = tid & 63;
    const int wm = (w >> 1) * 32, wn = (w & 1) * 128;
    const int fr = l & 15, g16 = l >> 4;

    const int arow = tid >> 2, aq = (tid & 3) * 8;   // A staging: 16B/thread

    f32x4 acc[2][8];
    #pragma unroll
    for (int i = 0; i < 2; ++i)
        #pragma unroll
        for (int j = 0; j < 8; ++j) acc[i][j] = (f32x4){0.f, 0.f, 0.f, 0.f};

    for (int k0 = 0; k0 < 512; k0 += 32) {
        __syncthreads();
        {   // stage A: 64 rows x 32 fp16
            const float* src = g + (size_t)(m0 + arow) * NT + (k0 + aq);
            float4 v0 = *(const float4*)src;
            float4 v1 = *(const float4*)(src + 4);
            h2 p0 = __builtin_amdgcn_cvt_pkrtz(v0.x, v0.y);
            h2 p1 = __builtin_amdgcn_cvt_pkrtz(v0.z, v0.w);
            h2 p2 = __builtin_amdgcn_cvt_pkrtz(v1.x, v1.y);
            h2 p3 = __builtin_amdgcn_cvt_pkrtz(v1.z, v1.w);
            *(float4*)&As[arow * ASTR + aq] =
                make_float4(__builtin_bit_cast(float, p0), __builtin_bit_cast(float, p1),
                            __builtin_bit_cast(float, p2), __builtin_bit_cast(float, p3));
        }
        {   // stage B: 256 rows x 32 fp16 (64B per thread-row)
            const float4* src = (const float4*)(Ht + (size_t)(n0 + tid) * NT + k0);
            float4 v0 = src[0], v1 = src[1], v2 = src[2], v3 = src[3];
            unsigned short* dst = &Bs[tid * BSTR];
            *(float4*)(dst)      = v0;
            *(float4*)(dst + 8)  = v1;
            *(float4*)(dst + 16) = v2;
            *(float4*)(dst + 24) = v3;
        }
        __syncthreads();

        f16x8 af[2], bf[8];
        #pragma unroll
        for (int i = 0; i < 2; ++i)
            af[i] = *(const f16x8*)&As[(wm + i * 16 + fr) * ASTR + g16 * 8];
        #pragma unroll
        for (int j = 0; j < 8; ++j)
            bf[j] = *(const f16x8*)&Bs[(wn + j * 16 + fr) * BSTR + g16 * 8];
        #pragma unroll
        for (int i = 0; i < 2; ++i)
            #pragma unroll
            for (int j = 0; j < 8; ++j)
                acc[i][j] = __builtin_amdgcn_mfma_f32_16x16x32_f16(af[i], bf[j], acc[i][j], 0, 0, 0);
    }

    #pragma unroll
    for (int i = 0; i < 2; ++i)
        #pragma unroll
        for (int j = 0; j < 8; ++j)
            #pragma unroll
            for (int v = 0; v < 4; ++v) {
                int row = m0 + wm + i * 16 + g16 * 4 + v;
                int col = n0 + wn + j * 16 + fr;
                filt[(size_t)row * NT + col] = f2h(acc[i][j][v]);
            }
}

// ---------------------------------------------------------------------------
// Kernel C: backprojection v7 -- fp16 window + fdot2, 4-way angle split.
// (unchanged from R9 except: filt is now fp16 -- staging loads ushorts and
//  packs pairs with shifts instead of cvt_pkrtz; window bits identical.)
// Grid = 4 quarters x 8 batch-quads x 64 tiles = 2048 blocks (8/CU).
// Index convention (R1/R3/R4-verified): ip = floor(q + cst), cst = 256.5-b0.
// ---------------------------------------------------------------------------
#define WCHUNK 15
#define WSTR   82

__global__ __launch_bounds__(256, 8) void backproject_kernel(const unsigned short* __restrict__ filt,
                                                             const float* __restrict__ ws,
                                                             float* __restrict__ out) {
    __shared__ __attribute__((aligned(16))) float4 win[WCHUNK][WSTR];
    __shared__ float cstbuf[WCHUNK];

    const int tid  = threadIdx.x;
    const int bidx = (int)blockIdx.x;
    const int quarter = bidx >> 9;         // 0..3: angle range
    const int rem  = bidx & 511;
    const int b    = (rem >> 6) * 4;       // batches b .. b+3
    const int tile = rem & 63;             // 8 x 8 tiles of 32x32
    const int i0 = (tile >> 3) * 32;
    const int j0 = (tile & 7) * 32;

    const float* trig = ws + 512;

    // compute-phase pixel mapping: wave = 16x16 px, lane = 2x2 px patch
    const int w  = tid >> 6;
    const int l  = tid & 63;
    const int wi = (w >> 1) * 16, wj = (w & 1) * 16;
    const int li = l >> 3, lj = l & 7;
    const int pi = i0 + wi + 2 * li;
    const int pj = j0 + wj + 2 * lj;
    const float xi = -1.f + ((float)pi + 0.5f) * DX_F;
    const float yj = -1.f + ((float)pj + 0.5f) * DX_F;

    // staging mapping: 16 threads per angle, angles sa in [0,15)
    const int sa = tid >> 4;
    const int st = tid & 15;
    const float xlo = -1.f + ((float)i0 + 0.5f) * DX_F;
    const float xhi = xlo + 31.f * DX_F;
    const float ylo = -1.f + ((float)j0 + 0.5f) * DX_F;
    const float yhi = ylo + 31.f * DX_F;

    const unsigned short* fb0 = filt + (size_t)b * (NPHI * NT);

    float acc[4][2][2];
    #pragma unroll
    for (int bb = 0; bb < 4; ++bb)
        #pragma unroll
        for (int di = 0; di < 2; ++di)
            #pragma unroll
            for (int dj = 0; dj < 2; ++dj) acc[bb][di][dj] = 0.f;

    const int pbeg = quarter * 180;
    for (int p0 = pbeg; p0 < pbeg + 180; p0 += WCHUNK) {
        __syncthreads();
        if (sa < WCHUNK) {
            const int p = p0 + sa;
            const float4 tg = *(const float4*)&trig[p * 4];
            const float umin = 256.5f + fminf(xlo * tg.x, xhi * tg.x)
                                      + fminf(ylo * tg.y, yhi * tg.y);
            const float b0f = floorf(umin) - 1.f;
            if (st == 0) cstbuf[sa] = 256.5f - b0f;
            const int base = (int)b0f + 5 * st - 1;
            unsigned short f[4][6];
            #pragma unroll
            for (int bb = 0; bb < 4; ++bb) {
                const unsigned short* rr = fb0 + (size_t)bb * (NPHI * NT) + (size_t)p * NT;
                #pragma unroll
                for (int k = 0; k < 6; ++k) {
                    int idx = base + k;
                    f[bb][k] = ((unsigned)idx < 512u) ? rr[idx] : (unsigned short)0;
                }
            }
            float4* wr = &win[sa][5 * st];
            #pragma unroll
            for (int j = 0; j < 5; ++j) {
                unsigned int u0 = (unsigned int)f[0][j] | ((unsigned int)f[0][j + 1] << 16);
                unsigned int u1 = (unsigned int)f[1][j] | ((unsigned int)f[1][j + 1] << 16);
                unsigned int u2 = (unsigned int)f[2][j] | ((unsigned int)f[2][j + 1] << 16);
                unsigned int u3 = (unsigned int)f[3][j] | ((unsigned int)f[3][j + 1] << 16);
                wr[j] = make_float4(__builtin_bit_cast(float, u0),
                                    __builtin_bit_cast(float, u1),
                                    __builtin_bit_cast(float, u2),
                                    __builtin_bit_cast(float, u3));
            }
        }
        __syncthreads();

        #pragma unroll 3
        for (int a = 0; a < WCHUNK; ++a) {
            const float4 tg = *(const float4*)&trig[(p0 + a) * 4]; // cd,sd,dci,dsj
            const float cst = cstbuf[a];
            const float4* wr = &win[a][0];
            const float u00 = xi * tg.x + yj * tg.y + cst;
            #pragma unroll
            for (int di = 0; di < 2; ++di) {
                float u = di ? (u00 + tg.z) : u00;
                #pragma unroll
                for (int dj = 0; dj < 2; ++dj) {
                    float fl = floorf(u);
                    float wv = u - fl;
                    int  ip  = (int)fl;
                    h2   wp  = __builtin_amdgcn_cvt_pkrtz(1.f - wv, wv);
                    float4 s = wr[ip];
                    acc[0][di][dj] = fdot2f(wp, s.x, acc[0][di][dj]);
                    acc[1][di][dj] = fdot2f(wp, s.y, acc[1][di][dj]);
                    acc[2][di][dj] = fdot2f(wp, s.z, acc[2][di][dj]);
                    acc[3][di][dj] = fdot2f(wp, s.w, acc[3][di][dj]);
                    u += tg.w;
                }
            }
        }
    }

    #pragma unroll
    for (int bb = 0; bb < 4; ++bb) {
        float* ob = out + (size_t)(b + bb) * (NH * NH) + (size_t)pi * NH + pj;
        #pragma unroll
        for (int di = 0; di < 2; ++di)
            #pragma unroll
            for (int dj = 0; dj < 2; ++dj)
                unsafeAtomicAdd(ob + di * NH + dj, acc[bb][di][dj] * DPHI_F);
    }
}

// ---------------------------------------------------------------------------
extern "C" void kernel_launch(void* const* d_in, const int* in_sizes, int n_in,
                              void* d_out, int out_size, void* d_ws, size_t ws_size,
                              hipStream_t stream) {
    const float* sinos = (const float*)d_in[0];   // [32,720,512] f32
    const float* kern  = (const float*)d_in[1];   // [257] f32
    float* out = (float*)d_out;                   // [32,256,256] f32
    float* ws  = (float*)d_ws;

    // ws layout: [0,4096) f32 tables; then Ht fp16 (512x512 = 512KB);
    // then filt fp16 (32*720*512 = 23.6MB). Total ~24.2MB.
    unsigned short* Ht    = (unsigned short*)(ws + 4096);
    unsigned short* filth = (unsigned short*)(ws + 4096 + 131072);

    hipMemsetAsync(d_out, 0, (size_t)out_size * sizeof(float), stream);
    hipLaunchKernelGGL(build_tables_kernel, dim3(1), dim3(512), 0, stream, kern, ws);
    hipLaunchKernelGGL(conv_gemm_kernel, dim3((23040 / 64) * 2), dim3(256), 0, stream,
                       sinos, Ht, filth);
    hipLaunchKernelGGL(backproject_kernel, dim3(4 * (NB / 4) * 64), dim3(256), 0, stream,
                       filth, ws, out);
}

// Round 12
// 226.471 us; speedup vs baseline: 5.0790x; 1.0988x over previous
//
#include <hip/hip_runtime.h>
#include <hip/hip_bf16.h>

// Geometry constants
#define NPHI 720
#define NT   512
#define NH   256
#define NB   32

#define DPHI_F   0.004363323129985824f   // pi/720
#define INV_DT_F 181.01933598375618f     // 256/sqrt(2)
#define DX_F     0.0078125f              // 2/256
#define W2PI_F   0.012271846303085130f   // 2*pi/512

typedef __fp16  h2   __attribute__((ext_vector_type(2)));   // cvt_pkrtz return type
typedef _Float16 f16x2 __attribute__((ext_vector_type(2))); // fdot2 operand type
typedef _Float16 f16x8 __attribute__((ext_vector_type(8))); // mfma A/B operand
typedef float    f32x4 __attribute__((ext_vector_type(4))); // mfma C/D

__device__ __forceinline__ float fdot2f(h2 a, float b_bits, float c) {
    return __builtin_amdgcn_fdot2(__builtin_bit_cast(f16x2, a),
                                  __builtin_bit_cast(f16x2, b_bits), c, false);
}
__device__ __forceinline__ unsigned int f2h(float x) {
    h2 p = __builtin_amdgcn_cvt_pkrtz(x, x);
    return (unsigned int)__builtin_bit_cast(ushort2, p).x;
}

// ---------------------------------------------------------------------------
// Kernel A: h = irfft(K,512) + trig table only (1 block; Ht moved out).
// ws floats: [0,512) h ; [512,3392) trig {c/DT,s/DT,c*DX/DT,s*DX/DT}
// ---------------------------------------------------------------------------
__global__ void build_tables_kernel(const float* __restrict__ kern,
                                    float* __restrict__ ws) {
    __shared__ float ctab[512];
    __shared__ float kk[257];
    const int t = threadIdx.x;            // 512 threads
    if (t < 257) kk[t] = kern[t];
    ctab[t] = cosf((float)t * W2PI_F);
    __syncthreads();

    float acc = 0.f;
    for (int k = 1; k < 256; ++k)
        acc += kk[k] * ctab[(k * t) & 511];
    float h = (kk[0] + ((t & 1) ? -kk[256] : kk[256]) + 2.f * acc) * (1.f / 512.f);
    ws[t] = h;

    for (int p = t; p < NPHI; p += 512) {
        float ang = ((float)p + 0.5f) * DPHI_F;
        float s, c;
        sincosf(ang, &s, &c);
        float cd = c * INV_DT_F;
        float sd = s * INV_DT_F;
        ws[512 + 4 * p + 0] = cd;
        ws[512 + 4 * p + 1] = sd;
        ws[512 + 4 * p + 2] = cd * DX_F;
        ws[512 + 4 * p + 3] = sd * DX_F;
    }
}

// ---------------------------------------------------------------------------
// Kernel A2: parallel Ht build + out zeroing (was: 1-block serial + memset).
// Blocks 0..63: Ht[o][m] fp16 pairs, rows o = bid*8..+7 (reads h from ws, L2).
// Blocks 64..191: zero out (float4 grid-stride).
// ---------------------------------------------------------------------------
__global__ __launch_bounds__(256) void ht_zero_kernel(const float* __restrict__ ws,
                                                      unsigned int* __restrict__ Ht,
                                                      float4* __restrict__ out4,
                                                      int nout4) {
    const int bid = (int)blockIdx.x;
    const int tid = threadIdx.x;
    if (bid < 64) {
        const int o  = bid * 8 + (tid >> 5);
        const int c0 = tid & 31;
        unsigned int* dst = Ht + (size_t)o * 256;
        #pragma unroll
        for (int k = 0; k < 8; ++k) {
            int mp = c0 + 32 * k;
            float lo = ws[(o - 2 * mp) & 511];
            float hi = ws[(o - 2 * mp - 1) & 511];
            h2 p = __builtin_amdgcn_cvt_pkrtz(lo, hi);
            dst[mp] = __builtin_bit_cast(unsigned int, p);
        }
    } else {
        const float4 z = make_float4(0.f, 0.f, 0.f, 0.f);
        for (int i = (bid - 64) * 256 + tid; i < nout4; i += 128 * 256)
            out4[i] = z;
    }
}

// ---------------------------------------------------------------------------
// Kernel B: filtering as GEMM on matrix cores (f32 output for BP staging).
// filt[r][o] = sum_m g[r][m] * h[(o-m)&511]  ==  G[23040x512] @ H[512x512],
// H[k][o] = Ht[o][k].  Tile 64(M) x 256(N) x 32(K); 4 waves, wave=32x128
// (2x8 frags of 16x16); 720 blocks.  LDS strides 40 fp16 (2-way free).
// mfma_f32_16x16x32_f16, m89-verified D layout; A/B share k-map.
// ---------------------------------------------------------------------------
#define ASTR 40
#define BSTR 40

__global__ __launch_bounds__(256) void conv_gemm_kernel(const float* __restrict__ g,
                                                        const unsigned short* __restrict__ Ht,
                                                        float* __restrict__ filt) {
    __shared__ __attribute__((aligned(16))) unsigned short As[64 * ASTR];
    __shared__ __attribute__((aligned(16))) unsigned short Bs[256 * BSTR];
    const int tid = threadIdx.x;
    const int m0 = ((int)blockIdx.x >> 1) * 64;
    const int n0 = ((int)blockIdx.x & 1) * 256;

    const int w = tid >> 6, l = tid & 63;
    const int wm = (w >> 1) * 32, wn = (w & 1) * 128;
    const int fr = l & 15, g16 = l >> 4;

    const int arow = tid >> 2, aq = (tid & 3) * 8;   // A staging: 16B/thread

    f32x4 acc[2][8];
    #pragma unroll
    for (int i = 0; i < 2; ++i)
        #pragma unroll
        for (int j = 0; j < 8; ++j) acc[i][j] = (f32x4){0.f, 0.f, 0.f, 0.f};

    for (int k0 = 0; k0 < 512; k0 += 32) {
        __syncthreads();
        {   // stage A: 64 rows x 32 fp16
            const float* src = g + (size_t)(m0 + arow) * NT + (k0 + aq);
            float4 v0 = *(const float4*)src;
            float4 v1 = *(const float4*)(src + 4);
            h2 p0 = __builtin_amdgcn_cvt_pkrtz(v0.x, v0.y);
            h2 p1 = __builtin_amdgcn_cvt_pkrtz(v0.z, v0.w);
            h2 p2 = __builtin_amdgcn_cvt_pkrtz(v1.x, v1.y);
            h2 p3 = __builtin_amdgcn_cvt_pkrtz(v1.z, v1.w);
            *(float4*)&As[arow * ASTR + aq] =
                make_float4(__builtin_bit_cast(float, p0), __builtin_bit_cast(float, p1),
                            __builtin_bit_cast(float, p2), __builtin_bit_cast(float, p3));
        }
        {   // stage B: 256 rows x 32 fp16 (64B per thread-row)
            const float4* src = (const float4*)(Ht + (size_t)(n0 + tid) * NT + k0);
            float4 v0 = src[0], v1 = src[1], v2 = src[2], v3 = src[3];
            unsigned short* dst = &Bs[tid * BSTR];
            *(float4*)(dst)      = v0;
            *(float4*)(dst + 8)  = v1;
            *(float4*)(dst + 16) = v2;
            *(float4*)(dst + 24) = v3;
        }
        __syncthreads();

        f16x8 af[2], bf[8];
        #pragma unroll
        for (int i = 0; i < 2; ++i)
            af[i] = *(const f16x8*)&As[(wm + i * 16 + fr) * ASTR + g16 * 8];
        #pragma unroll
        for (int j = 0; j < 8; ++j)
            bf[j] = *(const f16x8*)&Bs[(wn + j * 16 + fr) * BSTR + g16 * 8];
        #pragma unroll
        for (int i = 0; i < 2; ++i)
            #pragma unroll
            for (int j = 0; j < 8; ++j)
                acc[i][j] = __builtin_amdgcn_mfma_f32_16x16x32_f16(af[i], bf[j], acc[i][j], 0, 0, 0);
    }

    #pragma unroll
    for (int i = 0; i < 2; ++i)
        #pragma unroll
        for (int j = 0; j < 8; ++j)
            #pragma unroll
            for (int v = 0; v < 4; ++v) {
                int row = m0 + wm + i * 16 + g16 * 4 + v;
                int col = n0 + wn + j * 16 + fr;
                filt[(size_t)row * NT + col] = acc[i][j][v];
            }
}

// ---------------------------------------------------------------------------
// Kernel C: backprojection (R10-measured 186us version, verbatim).
// fp16 window + fdot2, 4-way angle split; f32 filt staged via cvt_pkrtz.
// Grid = 4 quarters x 8 batch-quads x 64 tiles = 2048 blocks (8/CU).
// Index convention (R1/R3/R4-verified): ip = floor(q + cst), cst = 256.5-b0.
// ---------------------------------------------------------------------------
#define WCHUNK 15
#define WSTR   82

__global__ __launch_bounds__(256, 8) void backproject_kernel(const float* __restrict__ filt,
                                                             const float* __restrict__ ws,
                                                             float* __restrict__ out) {
    __shared__ __attribute__((aligned(16))) float4 win[WCHUNK][WSTR];
    __shared__ float cstbuf[WCHUNK];

    const int tid  = threadIdx.x;
    const int bidx = (int)blockIdx.x;
    const int quarter = bidx >> 9;         // 0..3: angle range
    const int rem  = bidx & 511;
    const int b    = (rem >> 6) * 4;       // batches b .. b+3
    const int tile = rem & 63;             // 8 x 8 tiles of 32x32
    const int i0 = (tile >> 3) * 32;
    const int j0 = (tile & 7) * 32;

    const float* trig = ws + 512;

    // compute-phase pixel mapping: wave = 16x16 px, lane = 2x2 px patch
    const int w  = tid >> 6;
    const int l  = tid & 63;
    const int wi = (w >> 1) * 16, wj = (w & 1) * 16;
    const int li = l >> 3, lj = l & 7;
    const int pi = i0 + wi + 2 * li;
    const int pj = j0 + wj + 2 * lj;
    const float xi = -1.f + ((float)pi + 0.5f) * DX_F;
    const float yj = -1.f + ((float)pj + 0.5f) * DX_F;

    // staging mapping: 16 threads per angle, angles sa in [0,15)
    const int sa = tid >> 4;
    const int st = tid & 15;
    const float xlo = -1.f + ((float)i0 + 0.5f) * DX_F;
    const float xhi = xlo + 31.f * DX_F;
    const float ylo = -1.f + ((float)j0 + 0.5f) * DX_F;
    const float yhi = ylo + 31.f * DX_F;

    const float* fb0 = filt + (size_t)b * (NPHI * NT);

    float acc[4][2][2];
    #pragma unroll
    for (int bb = 0; bb < 4; ++bb)
        #pragma unroll
        for (int di = 0; di < 2; ++di)
            #pragma unroll
            for (int dj = 0; dj < 2; ++dj) acc[bb][di][dj] = 0.f;

    const int pbeg = quarter * 180;
    for (int p0 = pbeg; p0 < pbeg + 180; p0 += WCHUNK) {
        __syncthreads();
        if (sa < WCHUNK) {
            const int p = p0 + sa;
            const float4 tg = *(const float4*)&trig[p * 4];
            const float umin = 256.5f + fminf(xlo * tg.x, xhi * tg.x)
                                      + fminf(ylo * tg.y, yhi * tg.y);
            const float b0f = floorf(umin) - 1.f;
            if (st == 0) cstbuf[sa] = 256.5f - b0f;
            const int base = (int)b0f + 5 * st - 1;
            float f[4][6];
            #pragma unroll
            for (int bb = 0; bb < 4; ++bb) {
                const float* rr = fb0 + (size_t)bb * (NPHI * NT) + (size_t)p * NT;
                #pragma unroll
                for (int k = 0; k < 6; ++k) {
                    int idx = base + k;
                    f[bb][k] = ((unsigned)idx < 512u) ? rr[idx] : 0.f;
                }
            }
            float4* wr = &win[sa][5 * st];
            #pragma unroll
            for (int j = 0; j < 5; ++j) {
                h2 a0 = __builtin_amdgcn_cvt_pkrtz(f[0][j], f[0][j + 1]);
                h2 a1 = __builtin_amdgcn_cvt_pkrtz(f[1][j], f[1][j + 1]);
                h2 a2 = __builtin_amdgcn_cvt_pkrtz(f[2][j], f[2][j + 1]);
                h2 a3 = __builtin_amdgcn_cvt_pkrtz(f[3][j], f[3][j + 1]);
                wr[j] = make_float4(__builtin_bit_cast(float, a0),
                                    __builtin_bit_cast(float, a1),
                                    __builtin_bit_cast(float, a2),
                                    __builtin_bit_cast(float, a3));
            }
        }
        __syncthreads();

        #pragma unroll 3
        for (int a = 0; a < WCHUNK; ++a) {
            const float4 tg = *(const float4*)&trig[(p0 + a) * 4]; // cd,sd,dci,dsj
            const float cst = cstbuf[a];
            const float4* wr = &win[a][0];
            const float u00 = xi * tg.x + yj * tg.y + cst;
            #pragma unroll
            for (int di = 0; di < 2; ++di) {
                float u = di ? (u00 + tg.z) : u00;
                #pragma unroll
                for (int dj = 0; dj < 2; ++dj) {
                    float fl = floorf(u);
                    float wv = u - fl;
                    int  ip  = (int)fl;
                    h2   wp  = __builtin_amdgcn_cvt_pkrtz(1.f - wv, wv);
                    float4 s = wr[ip];
                    acc[0][di][dj] = fdot2f(wp, s.x, acc[0][di][dj]);
                    acc[1][di][dj] = fdot2f(wp, s.y, acc[1][di][dj]);
                    acc[2][di][dj] = fdot2f(wp, s.z, acc[2][di][dj]);
                    acc[3][di][dj] = fdot2f(wp, s.w, acc[3][di][dj]);
                    u += tg.w;
                }
            }
        }
    }

    #pragma unroll
    for (int bb = 0; bb < 4; ++bb) {
        float* ob = out + (size_t)(b + bb) * (NH * NH) + (size_t)pi * NH + pj;
        #pragma unroll
        for (int di = 0; di < 2; ++di)
            #pragma unroll
            for (int dj = 0; dj < 2; ++dj)
                unsafeAtomicAdd(ob + di * NH + dj, acc[bb][di][dj] * DPHI_F);
    }
}

// ---------------------------------------------------------------------------
extern "C" void kernel_launch(void* const* d_in, const int* in_sizes, int n_in,
                              void* d_out, int out_size, void* d_ws, size_t ws_size,
                              hipStream_t stream) {
    const float* sinos = (const float*)d_in[0];   // [32,720,512] f32
    const float* kern  = (const float*)d_in[1];   // [257] f32
    float* out = (float*)d_out;                   // [32,256,256] f32
    float* ws  = (float*)d_ws;

    // ws layout: [0,4096) f32 tables; [4096, 4096+131072) Ht fp16 (512KB);
    // then filt f32 (32*720*512 floats = 47.2MB).
    unsigned int*   Ht32 = (unsigned int*)(ws + 4096);
    unsigned short* Ht   = (unsigned short*)Ht32;
    float*          filt = ws + 4096 + 131072;

    hipLaunchKernelGGL(build_tables_kernel, dim3(1), dim3(512), 0, stream, kern, ws);
    hipLaunchKernelGGL(ht_zero_kernel, dim3(192), dim3(256), 0, stream,
                       ws, Ht32, (float4*)out, out_size / 4);
    hipLaunchKernelGGL(conv_gemm_kernel, dim3((23040 / 64) * 2), dim3(256), 0, stream,
                       sinos, Ht, filt);
    hipLaunchKernelGGL(backproject_kernel, dim3(4 * (NB / 4) * 64), dim3(256), 0, stream,
                       filt, ws, out);
}

// Round 13
// 225.641 us; speedup vs baseline: 5.0977x; 1.0037x over previous
//
#include <hip/hip_runtime.h>
#include <hip/hip_bf16.h>

// Geometry constants
#define NPHI 720
#define NT   512
#define NH   256
#define NB   32

#define DPHI_F   0.004363323129985824f   // pi/720
#define INV_DT_F 181.01933598375618f     // 256/sqrt(2)
#define DX_F     0.0078125f              // 2/256
#define W2PI_F   0.012271846303085130f   // 2*pi/512

#define FSTR 520   // padded filt row stride (4 zero | 512 data | 4 zero)

typedef __fp16  h2   __attribute__((ext_vector_type(2)));   // cvt_pkrtz return type
typedef _Float16 f16x2 __attribute__((ext_vector_type(2))); // fdot2 operand type
typedef _Float16 f16x8 __attribute__((ext_vector_type(8))); // mfma A/B operand
typedef float    f32x4 __attribute__((ext_vector_type(4))); // mfma C/D
typedef float    f32x4u __attribute__((ext_vector_type(4), aligned(4)));
typedef float    f32x2u __attribute__((ext_vector_type(2), aligned(4)));

__device__ __forceinline__ float fdot2f(h2 a, float b_bits, float c) {
    return __builtin_amdgcn_fdot2(__builtin_bit_cast(f16x2, a),
                                  __builtin_bit_cast(f16x2, b_bits), c, false);
}

// ---------------------------------------------------------------------------
// Setup kernel (single dispatch):
//  blocks [0,64):    Ht[o][m] = h[(o-m)&511] fp16 pairs (h computed locally)
//  blocks [64,67):   trig table -> ws[512 + 4p ..]
//  blocks [67,195):  zero out (float4 grid-stride)
//  blocks [195,323): zero filt row pads ([0,4) and [516,520) of each row)
// ---------------------------------------------------------------------------
__global__ __launch_bounds__(256) void setup_kernel(const float* __restrict__ kern,
                                                    float* __restrict__ ws,
                                                    unsigned int* __restrict__ Ht,
                                                    float4* __restrict__ out4,
                                                    float* __restrict__ filt) {
    const int bid = (int)blockIdx.x;
    const int tid = threadIdx.x;
    if (bid < 64) {
        __shared__ float ctab[512];
        __shared__ float kk[257];
        __shared__ float hloc[512];
        kk[tid] = kern[tid];
        if (tid == 0) kk[256] = kern[256];
        ctab[tid]       = cosf((float)tid * W2PI_F);
        ctab[tid + 256] = cosf((float)(tid + 256) * W2PI_F);
        __syncthreads();
        for (int tt = tid; tt < 512; tt += 256) {
            float acc = 0.f;
            for (int k = 1; k < 256; ++k)
                acc += kk[k] * ctab[(k * tt) & 511];
            hloc[tt] = (kk[0] + ((tt & 1) ? -kk[256] : kk[256]) + 2.f * acc) * (1.f / 512.f);
        }
        __syncthreads();
        const int o  = bid * 8 + (tid >> 5);
        const int c0 = tid & 31;
        unsigned int* dst = Ht + (size_t)o * 256;
        #pragma unroll
        for (int k = 0; k < 8; ++k) {
            int mp = c0 + 32 * k;
            h2 p = __builtin_amdgcn_cvt_pkrtz(hloc[(o - 2 * mp) & 511],
                                              hloc[(o - 2 * mp - 1) & 511]);
            dst[mp] = __builtin_bit_cast(unsigned int, p);
        }
    } else if (bid < 67) {
        int p = (bid - 64) * 256 + tid;
        if (p < NPHI) {
            float ang = ((float)p + 0.5f) * DPHI_F;
            float s, c;
            sincosf(ang, &s, &c);
            float cd = c * INV_DT_F;
            float sd = s * INV_DT_F;
            ws[512 + 4 * p + 0] = cd;
            ws[512 + 4 * p + 1] = sd;
            ws[512 + 4 * p + 2] = cd * DX_F;
            ws[512 + 4 * p + 3] = sd * DX_F;
        }
    } else if (bid < 195) {
        const float4 z = make_float4(0.f, 0.f, 0.f, 0.f);
        const int nout4 = NB * NH * NH / 4;
        for (int i = (bid - 67) * 256 + tid; i < nout4; i += 128 * 256)
            out4[i] = z;
    } else {
        const float4 z = make_float4(0.f, 0.f, 0.f, 0.f);
        const int rb = (bid - 195) * 180;           // 23040 / 128 = 180 rows/block
        for (int i = tid; i < 360; i += 256) {
            int row = rb + (i >> 1);
            float* p = filt + (size_t)row * FSTR + ((i & 1) ? 516 : 0);
            *(float4*)p = z;
        }
    }
}

// ---------------------------------------------------------------------------
// Kernel B: filtering as GEMM on matrix cores, single N pass.
// filt[r][o] = sum_m g[r][m] * h[(o-m)&511]  ==  G[23040x512] @ H[512x512].
// Tile 32(M) x 512(N) x 32(K); 4 waves, wave = 32x128 (2x8 frags of 16x16);
// 720 blocks (G read once: FETCH ~46MB).  LDS strides 40 fp16 (2-way free).
// mfma_f32_16x16x32_f16, m89-verified D layout; A/B share k-map.
// Output written f32 into the PADDED filt (row stride 520, data at +4).
// ---------------------------------------------------------------------------
#define ASTR 40
#define BSTR 40

__global__ __launch_bounds__(256) void conv_gemm_kernel(const float* __restrict__ g,
                                                        const unsigned short* __restrict__ Ht,
                                                        float* __restrict__ filt) {
    __shared__ __attribute__((aligned(16))) unsigned short As[32 * ASTR];
    __shared__ __attribute__((aligned(16))) unsigned short Bs[512 * BSTR];
    const int tid = threadIdx.x;
    const int m0 = (int)blockIdx.x * 32;

    const int w = tid >> 6, l = tid & 63;
    const int wn = w * 128;
    const int fr = l & 15, g16 = l >> 4;

    const int arow = tid >> 3, aq = (tid & 7) * 4;   // A staging: 8 thr/row, float4 each

    f32x4 acc[2][8];
    #pragma unroll
    for (int i = 0; i < 2; ++i)
        #pragma unroll
        for (int j = 0; j < 8; ++j) acc[i][j] = (f32x4){0.f, 0.f, 0.f, 0.f};

    for (int k0 = 0; k0 < 512; k0 += 32) {
        __syncthreads();
        {   // stage A: 32 rows x 32 fp16
            const float* src = g + (size_t)(m0 + arow) * NT + (k0 + aq);
            float4 v = *(const float4*)src;
            h2 p0 = __builtin_amdgcn_cvt_pkrtz(v.x, v.y);
            h2 p1 = __builtin_amdgcn_cvt_pkrtz(v.z, v.w);
            *(uint2*)&As[arow * ASTR + aq] =
                make_uint2(__builtin_bit_cast(unsigned int, p0),
                           __builtin_bit_cast(unsigned int, p1));
        }
        {   // stage B: 512 rows x 32 fp16, 2 rows per thread
            #pragma unroll
            for (int rr = 0; rr < 2; ++rr) {
                const int row = tid + 256 * rr;
                const float4* src = (const float4*)(Ht + (size_t)row * NT + k0);
                float4 v0 = src[0], v1 = src[1], v2 = src[2], v3 = src[3];
                unsigned short* dst = &Bs[row * BSTR];
                *(float4*)(dst)      = v0;
                *(float4*)(dst + 8)  = v1;
                *(float4*)(dst + 16) = v2;
                *(float4*)(dst + 24) = v3;
            }
        }
        __syncthreads();

        f16x8 af[2], bf[8];
        #pragma unroll
        for (int i = 0; i < 2; ++i)
            af[i] = *(const f16x8*)&As[(i * 16 + fr) * ASTR + g16 * 8];
        #pragma unroll
        for (int j = 0; j < 8; ++j)
            bf[j] = *(const f16x8*)&Bs[(wn + j * 16 + fr) * BSTR + g16 * 8];
        #pragma unroll
        for (int i = 0; i < 2; ++i)
            #pragma unroll
            for (int j = 0; j < 8; ++j)
                acc[i][j] = __builtin_amdgcn_mfma_f32_16x16x32_f16(af[i], bf[j], acc[i][j], 0, 0, 0);
    }

    #pragma unroll
    for (int i = 0; i < 2; ++i)
        #pragma unroll
        for (int j = 0; j < 8; ++j)
            #pragma unroll
            for (int v = 0; v < 4; ++v) {
                int row = m0 + i * 16 + g16 * 4 + v;
                int col = wn + j * 16 + fr;
                filt[(size_t)row * FSTR + 4 + col] = acc[i][j][v];
            }
}

// ---------------------------------------------------------------------------
// Kernel C: backprojection v8 -- fp16 window + fdot2, 4-way angle split,
// branch-free vector staging from the PADDED filt.
// Grid = 4 quarters x 8 batch-quads x 64 tiles = 2048 blocks (8/CU).
// Staging (st < 14 only; slots >= 70 unreachable since ip <= 65):
//   base = b0 + 5*st - 1, basec = min(base, 506): cells [basec..basec+5] via
//   one f32x4u + one f32x2u load (pads guarantee in-bounds & zeros);
//   writes slots [basec-b0+1 .. +5]. Clamped threads duplicate slots up to
//   512-b0 with identical values; slots beyond have cells > 512, never read.
// Index convention (R1/R3/R4-verified): ip = floor(q + cst), cst = 256.5-b0.
// ---------------------------------------------------------------------------
#define WCHUNK 15
#define WSTR   82

__global__ __launch_bounds__(256, 8) void backproject_kernel(const float* __restrict__ filt,
                                                             const float* __restrict__ ws,
                                                             float* __restrict__ out) {
    __shared__ __attribute__((aligned(16))) float4 win[WCHUNK][WSTR];
    __shared__ float cstbuf[WCHUNK];

    const int tid  = threadIdx.x;
    const int bidx = (int)blockIdx.x;
    const int quarter = bidx >> 9;         // 0..3: angle range
    const int rem  = bidx & 511;
    const int b    = (rem >> 6) * 4;       // batches b .. b+3
    const int tile = rem & 63;             // 8 x 8 tiles of 32x32
    const int i0 = (tile >> 3) * 32;
    const int j0 = (tile & 7) * 32;

    const float* trig = ws + 512;

    // compute-phase pixel mapping: wave = 16x16 px, lane = 2x2 px patch
    const int w  = tid >> 6;
    const int l  = tid & 63;
    const int wi = (w >> 1) * 16, wj = (w & 1) * 16;
    const int li = l >> 3, lj = l & 7;
    const int pi = i0 + wi + 2 * li;
    const int pj = j0 + wj + 2 * lj;
    const float xi = -1.f + ((float)pi + 0.5f) * DX_F;
    const float yj = -1.f + ((float)pj + 0.5f) * DX_F;

    // staging mapping: 16 threads per angle (st < 14 active), sa in [0,15)
    const int sa = tid >> 4;
    const int st = tid & 15;
    const float xlo = -1.f + ((float)i0 + 0.5f) * DX_F;
    const float xhi = xlo + 31.f * DX_F;
    const float ylo = -1.f + ((float)j0 + 0.5f) * DX_F;
    const float yhi = ylo + 31.f * DX_F;

    const float* fb0 = filt + (size_t)b * (NPHI * FSTR);

    float acc[4][2][2];
    #pragma unroll
    for (int bb = 0; bb < 4; ++bb)
        #pragma unroll
        for (int di = 0; di < 2; ++di)
            #pragma unroll
            for (int dj = 0; dj < 2; ++dj) acc[bb][di][dj] = 0.f;

    const int pbeg = quarter * 180;
    for (int p0 = pbeg; p0 < pbeg + 180; p0 += WCHUNK) {
        __syncthreads();
        if (sa < WCHUNK && st < 14) {
            const int p = p0 + sa;
            const float4 tg = *(const float4*)&trig[p * 4];
            const float umin = 256.5f + fminf(xlo * tg.x, xhi * tg.x)
                                      + fminf(ylo * tg.y, yhi * tg.y);
            const float b0f = floorf(umin) - 1.f;
            if (st == 0) cstbuf[sa] = 256.5f - b0f;
            const int b0 = (int)b0f;
            const int base  = b0 + 5 * st - 1;
            const int basec = min(base, 506);
            float f[4][6];
            #pragma unroll
            for (int bb = 0; bb < 4; ++bb) {
                const float* rr = fb0 + (size_t)bb * (NPHI * FSTR) + (size_t)p * FSTR + 4 + basec;
                f32x4u v0 = *(const f32x4u*)rr;
                f32x2u v1 = *(const f32x2u*)(rr + 4);
                f[bb][0] = v0[0]; f[bb][1] = v0[1]; f[bb][2] = v0[2];
                f[bb][3] = v0[3]; f[bb][4] = v1[0]; f[bb][5] = v1[1];
            }
            float4* wr = &win[sa][basec - b0 + 1];
            #pragma unroll
            for (int j = 0; j < 5; ++j) {
                h2 a0 = __builtin_amdgcn_cvt_pkrtz(f[0][j], f[0][j + 1]);
                h2 a1 = __builtin_amdgcn_cvt_pkrtz(f[1][j], f[1][j + 1]);
                h2 a2 = __builtin_amdgcn_cvt_pkrtz(f[2][j], f[2][j + 1]);
                h2 a3 = __builtin_amdgcn_cvt_pkrtz(f[3][j], f[3][j + 1]);
                wr[j] = make_float4(__builtin_bit_cast(float, a0),
                                    __builtin_bit_cast(float, a1),
                                    __builtin_bit_cast(float, a2),
                                    __builtin_bit_cast(float, a3));
            }
        }
        __syncthreads();

        #pragma unroll 3
        for (int a = 0; a < WCHUNK; ++a) {
            const float4 tg = *(const float4*)&trig[(p0 + a) * 4]; // cd,sd,dci,dsj
            const float cst = cstbuf[a];
            const float4* wr = &win[a][0];
            const float u00 = xi * tg.x + yj * tg.y + cst;
            #pragma unroll
            for (int di = 0; di < 2; ++di) {
                float u = di ? (u00 + tg.z) : u00;
                #pragma unroll
                for (int dj = 0; dj < 2; ++dj) {
                    float fl = floorf(u);
                    float wv = u - fl;
                    int  ip  = (int)fl;
                    h2   wp  = __builtin_amdgcn_cvt_pkrtz(1.f - wv, wv);
                    float4 s = wr[ip];
                    acc[0][di][dj] = fdot2f(wp, s.x, acc[0][di][dj]);
                    acc[1][di][dj] = fdot2f(wp, s.y, acc[1][di][dj]);
                    acc[2][di][dj] = fdot2f(wp, s.z, acc[2][di][dj]);
                    acc[3][di][dj] = fdot2f(wp, s.w, acc[3][di][dj]);
                    u += tg.w;
                }
            }
        }
    }

    #pragma unroll
    for (int bb = 0; bb < 4; ++bb) {
        float* ob = out + (size_t)(b + bb) * (NH * NH) + (size_t)pi * NH + pj;
        #pragma unroll
        for (int di = 0; di < 2; ++di)
            #pragma unroll
            for (int dj = 0; dj < 2; ++dj)
                unsafeAtomicAdd(ob + di * NH + dj, acc[bb][di][dj] * DPHI_F);
    }
}

// ---------------------------------------------------------------------------
extern "C" void kernel_launch(void* const* d_in, const int* in_sizes, int n_in,
                              void* d_out, int out_size, void* d_ws, size_t ws_size,
                              hipStream_t stream) {
    const float* sinos = (const float*)d_in[0];   // [32,720,512] f32
    const float* kern  = (const float*)d_in[1];   // [257] f32
    float* out = (float*)d_out;                   // [32,256,256] f32
    float* ws  = (float*)d_ws;

    // ws layout: [0,4096) f32 tables; [4096, +131072) Ht fp16 (512KB);
    // then padded filt f32 (23040 x 520 floats = 47.9MB).
    unsigned int*   Ht32 = (unsigned int*)(ws + 4096);
    unsigned short* Ht   = (unsigned short*)Ht32;
    float*          filt = ws + 4096 + 131072;

    hipLaunchKernelGGL(setup_kernel, dim3(323), dim3(256), 0, stream,
                       kern, ws, Ht32, (float4*)out, filt);
    hipLaunchKernelGGL(conv_gemm_kernel, dim3(23040 / 32), dim3(256), 0, stream,
                       sinos, Ht, filt);
    hipLaunchKernelGGL(backproject_kernel, dim3(4 * (NB / 4) * 64), dim3(256), 0, stream,
                       filt, ws, out);
}

// Round 14
// 206.258 us; speedup vs baseline: 5.5767x; 1.0940x over previous
//
#include <hip/hip_runtime.h>
#include <hip/hip_bf16.h>

// Geometry constants
#define NPHI 720
#define NT   512
#define NH   256
#define NB   32

#define DPHI_F   0.004363323129985824f   // pi/720
#define INV_DT_F 181.01933598375618f     // 256/sqrt(2)
#define DX_F     0.0078125f              // 2/256
#define W2PI_F   0.012271846303085130f   // 2*pi/512

#define FSTR 520   // padded filt row stride (4 zero | 512 data | 4 zero)

typedef __fp16  h2   __attribute__((ext_vector_type(2)));   // cvt_pkrtz return type
typedef _Float16 f16x2 __attribute__((ext_vector_type(2))); // fdot2 operand type
typedef _Float16 f16x8 __attribute__((ext_vector_type(8))); // mfma A/B operand
typedef float    f32x4 __attribute__((ext_vector_type(4))); // mfma C/D
typedef float    f32x4u __attribute__((ext_vector_type(4), aligned(4)));
typedef float    f32x2u __attribute__((ext_vector_type(2), aligned(4)));

__device__ __forceinline__ float fdot2f(h2 a, float b_bits, float c) {
    return __builtin_amdgcn_fdot2(__builtin_bit_cast(f16x2, a),
                                  __builtin_bit_cast(f16x2, b_bits), c, false);
}

// ---------------------------------------------------------------------------
// Setup kernel (single dispatch):
//  blocks [0,64):    Ht[o][m] = h[(o-m)&511] fp16 pairs (h computed locally)
//  blocks [64,67):   trig table -> ws[512 + 4p ..]
//  blocks [67,195):  zero out (float4 grid-stride)
//  blocks [195,323): zero filt row pads ([0,4) and [516,520) of each row)
// ---------------------------------------------------------------------------
__global__ __launch_bounds__(256) void setup_kernel(const float* __restrict__ kern,
                                                    float* __restrict__ ws,
                                                    unsigned int* __restrict__ Ht,
                                                    float4* __restrict__ out4,
                                                    float* __restrict__ filt) {
    const int bid = (int)blockIdx.x;
    const int tid = threadIdx.x;
    if (bid < 64) {
        __shared__ float ctab[512];
        __shared__ float kk[257];
        __shared__ float hloc[512];
        kk[tid] = kern[tid];
        if (tid == 0) kk[256] = kern[256];
        ctab[tid]       = cosf((float)tid * W2PI_F);
        ctab[tid + 256] = cosf((float)(tid + 256) * W2PI_F);
        __syncthreads();
        for (int tt = tid; tt < 512; tt += 256) {
            float acc = 0.f;
            for (int k = 1; k < 256; ++k)
                acc += kk[k] * ctab[(k * tt) & 511];
            hloc[tt] = (kk[0] + ((tt & 1) ? -kk[256] : kk[256]) + 2.f * acc) * (1.f / 512.f);
        }
        __syncthreads();
        const int o  = bid * 8 + (tid >> 5);
        const int c0 = tid & 31;
        unsigned int* dst = Ht + (size_t)o * 256;
        #pragma unroll
        for (int k = 0; k < 8; ++k) {
            int mp = c0 + 32 * k;
            h2 p = __builtin_amdgcn_cvt_pkrtz(hloc[(o - 2 * mp) & 511],
                                              hloc[(o - 2 * mp - 1) & 511]);
            dst[mp] = __builtin_bit_cast(unsigned int, p);
        }
    } else if (bid < 67) {
        int p = (bid - 64) * 256 + tid;
        if (p < NPHI) {
            float ang = ((float)p + 0.5f) * DPHI_F;
            float s, c;
            sincosf(ang, &s, &c);
            float cd = c * INV_DT_F;
            float sd = s * INV_DT_F;
            ws[512 + 4 * p + 0] = cd;
            ws[512 + 4 * p + 1] = sd;
            ws[512 + 4 * p + 2] = cd * DX_F;
            ws[512 + 4 * p + 3] = sd * DX_F;
        }
    } else if (bid < 195) {
        const float4 z = make_float4(0.f, 0.f, 0.f, 0.f);
        const int nout4 = NB * NH * NH / 4;
        for (int i = (bid - 67) * 256 + tid; i < nout4; i += 128 * 256)
            out4[i] = z;
    } else {
        const float4 z = make_float4(0.f, 0.f, 0.f, 0.f);
        const int rb = (bid - 195) * 180;           // 23040 / 128 = 180 rows/block
        for (int i = tid; i < 360; i += 256) {
            int row = rb + (i >> 1);
            float* p = filt + (size_t)row * FSTR + ((i & 1) ? 516 : 0);
            *(float4*)p = z;
        }
    }
}

// ---------------------------------------------------------------------------
// Kernel B: filtering as GEMM on matrix cores, single N pass, 64-row M tile.
// filt[r][o] = sum_m g[r][m] * h[(o-m)&511]  ==  G[23040x512] @ H[512x512].
// Tile 64(M) x 512(N) x 32(K); 512 threads = 8 waves, wave = 32x128
// (2x8 frags of 16x16); 360 blocks (G read once; B staged once per k-step
// by 512 threads -> half R12's, quarter R13's staging per MFMA).
// LDS: As 5KB + Bs 40KB = 45KB -> 2 blocks/CU (16 waves).
// mfma_f32_16x16x32_f16, m89-verified D layout; A/B share k-map.
// Output written f32 into the PADDED filt (row stride 520, data at +4).
// ---------------------------------------------------------------------------
#define ASTR 40
#define BSTR 40

__global__ __launch_bounds__(512) void conv_gemm_kernel(const float* __restrict__ g,
                                                        const unsigned short* __restrict__ Ht,
                                                        float* __restrict__ filt) {
    __shared__ __attribute__((aligned(16))) unsigned short As[64 * ASTR];
    __shared__ __attribute__((aligned(16))) unsigned short Bs[512 * BSTR];
    const int tid = threadIdx.x;
    const int m0 = (int)blockIdx.x * 64;

    const int w = tid >> 6, l = tid & 63;
    const int wm = (w >> 2) * 32;          // 0 or 32
    const int wn = (w & 3) * 128;          // 0,128,256,384
    const int fr = l & 15, g16 = l >> 4;

    const int arow = tid >> 3, aq = (tid & 7) * 4;   // A staging: 8 thr/row, float4 each

    f32x4 acc[2][8];
    #pragma unroll
    for (int i = 0; i < 2; ++i)
        #pragma unroll
        for (int j = 0; j < 8; ++j) acc[i][j] = (f32x4){0.f, 0.f, 0.f, 0.f};

    for (int k0 = 0; k0 < 512; k0 += 32) {
        __syncthreads();
        {   // stage A: 64 rows x 32 fp16
            const float* src = g + (size_t)(m0 + arow) * NT + (k0 + aq);
            float4 v = *(const float4*)src;
            h2 p0 = __builtin_amdgcn_cvt_pkrtz(v.x, v.y);
            h2 p1 = __builtin_amdgcn_cvt_pkrtz(v.z, v.w);
            *(uint2*)&As[arow * ASTR + aq] =
                make_uint2(__builtin_bit_cast(unsigned int, p0),
                           __builtin_bit_cast(unsigned int, p1));
        }
        {   // stage B: 512 rows x 32 fp16, 1 row per thread (64B)
            const float4* src = (const float4*)(Ht + (size_t)tid * NT + k0);
            float4 v0 = src[0], v1 = src[1], v2 = src[2], v3 = src[3];
            unsigned short* dst = &Bs[tid * BSTR];
            *(float4*)(dst)      = v0;
            *(float4*)(dst + 8)  = v1;
            *(float4*)(dst + 16) = v2;
            *(float4*)(dst + 24) = v3;
        }
        __syncthreads();

        f16x8 af[2], bf[8];
        #pragma unroll
        for (int i = 0; i < 2; ++i)
            af[i] = *(const f16x8*)&As[(wm + i * 16 + fr) * ASTR + g16 * 8];
        #pragma unroll
        for (int j = 0; j < 8; ++j)
            bf[j] = *(const f16x8*)&Bs[(wn + j * 16 + fr) * BSTR + g16 * 8];
        #pragma unroll
        for (int i = 0; i < 2; ++i)
            #pragma unroll
            for (int j = 0; j < 8; ++j)
                acc[i][j] = __builtin_amdgcn_mfma_f32_16x16x32_f16(af[i], bf[j], acc[i][j], 0, 0, 0);
    }

    #pragma unroll
    for (int i = 0; i < 2; ++i)
        #pragma unroll
        for (int j = 0; j < 8; ++j)
            #pragma unroll
            for (int v = 0; v < 4; ++v) {
                int row = m0 + wm + i * 16 + g16 * 4 + v;
                int col = wn + j * 16 + fr;
                filt[(size_t)row * FSTR + 4 + col] = acc[i][j][v];
            }
}

// ---------------------------------------------------------------------------
// Kernel C: backprojection (R13-measured 165us version, verbatim).
// fp16 window + fdot2, 4-way angle split, branch-free vector staging from
// the PADDED filt. Grid = 4 x 8 x 64 = 2048 blocks (8/CU).
// Index convention (R1/R3/R4-verified): ip = floor(q + cst), cst = 256.5-b0.
// ---------------------------------------------------------------------------
#define WCHUNK 15
#define WSTR   82

__global__ __launch_bounds__(256, 8) void backproject_kernel(const float* __restrict__ filt,
                                                             const float* __restrict__ ws,
                                                             float* __restrict__ out) {
    __shared__ __attribute__((aligned(16))) float4 win[WCHUNK][WSTR];
    __shared__ float cstbuf[WCHUNK];

    const int tid  = threadIdx.x;
    const int bidx = (int)blockIdx.x;
    const int quarter = bidx >> 9;         // 0..3: angle range
    const int rem  = bidx & 511;
    const int b    = (rem >> 6) * 4;       // batches b .. b+3
    const int tile = rem & 63;             // 8 x 8 tiles of 32x32
    const int i0 = (tile >> 3) * 32;
    const int j0 = (tile & 7) * 32;

    const float* trig = ws + 512;

    // compute-phase pixel mapping: wave = 16x16 px, lane = 2x2 px patch
    const int w  = tid >> 6;
    const int l  = tid & 63;
    const int wi = (w >> 1) * 16, wj = (w & 1) * 16;
    const int li = l >> 3, lj = l & 7;
    const int pi = i0 + wi + 2 * li;
    const int pj = j0 + wj + 2 * lj;
    const float xi = -1.f + ((float)pi + 0.5f) * DX_F;
    const float yj = -1.f + ((float)pj + 0.5f) * DX_F;

    // staging mapping: 16 threads per angle (st < 14 active), sa in [0,15)
    const int sa = tid >> 4;
    const int st = tid & 15;
    const float xlo = -1.f + ((float)i0 + 0.5f) * DX_F;
    const float xhi = xlo + 31.f * DX_F;
    const float ylo = -1.f + ((float)j0 + 0.5f) * DX_F;
    const float yhi = ylo + 31.f * DX_F;

    const float* fb0 = filt + (size_t)b * (NPHI * FSTR);

    float acc[4][2][2];
    #pragma unroll
    for (int bb = 0; bb < 4; ++bb)
        #pragma unroll
        for (int di = 0; di < 2; ++di)
            #pragma unroll
            for (int dj = 0; dj < 2; ++dj) acc[bb][di][dj] = 0.f;

    const int pbeg = quarter * 180;
    for (int p0 = pbeg; p0 < pbeg + 180; p0 += WCHUNK) {
        __syncthreads();
        if (sa < WCHUNK && st < 14) {
            const int p = p0 + sa;
            const float4 tg = *(const float4*)&trig[p * 4];
            const float umin = 256.5f + fminf(xlo * tg.x, xhi * tg.x)
                                      + fminf(ylo * tg.y, yhi * tg.y);
            const float b0f = floorf(umin) - 1.f;
            if (st == 0) cstbuf[sa] = 256.5f - b0f;
            const int b0 = (int)b0f;
            const int base  = b0 + 5 * st - 1;
            const int basec = min(base, 506);
            float f[4][6];
            #pragma unroll
            for (int bb = 0; bb < 4; ++bb) {
                const float* rr = fb0 + (size_t)bb * (NPHI * FSTR) + (size_t)p * FSTR + 4 + basec;
                f32x4u v0 = *(const f32x4u*)rr;
                f32x2u v1 = *(const f32x2u*)(rr + 4);
                f[bb][0] = v0[0]; f[bb][1] = v0[1]; f[bb][2] = v0[2];
                f[bb][3] = v0[3]; f[bb][4] = v1[0]; f[bb][5] = v1[1];
            }
            float4* wr = &win[sa][basec - b0 + 1];
            #pragma unroll
            for (int j = 0; j < 5; ++j) {
                h2 a0 = __builtin_amdgcn_cvt_pkrtz(f[0][j], f[0][j + 1]);
                h2 a1 = __builtin_amdgcn_cvt_pkrtz(f[1][j], f[1][j + 1]);
                h2 a2 = __builtin_amdgcn_cvt_pkrtz(f[2][j], f[2][j + 1]);
                h2 a3 = __builtin_amdgcn_cvt_pkrtz(f[3][j], f[3][j + 1]);
                wr[j] = make_float4(__builtin_bit_cast(float, a0),
                                    __builtin_bit_cast(float, a1),
                                    __builtin_bit_cast(float, a2),
                                    __builtin_bit_cast(float, a3));
            }
        }
        __syncthreads();

        #pragma unroll 3
        for (int a = 0; a < WCHUNK; ++a) {
            const float4 tg = *(const float4*)&trig[(p0 + a) * 4]; // cd,sd,dci,dsj
            const float cst = cstbuf[a];
            const float4* wr = &win[a][0];
            const float u00 = xi * tg.x + yj * tg.y + cst;
            #pragma unroll
            for (int di = 0; di < 2; ++di) {
                float u = di ? (u00 + tg.z) : u00;
                #pragma unroll
                for (int dj = 0; dj < 2; ++dj) {
                    float fl = floorf(u);
                    float wv = u - fl;
                    int  ip  = (int)fl;
                    h2   wp  = __builtin_amdgcn_cvt_pkrtz(1.f - wv, wv);
                    float4 s = wr[ip];
                    acc[0][di][dj] = fdot2f(wp, s.x, acc[0][di][dj]);
                    acc[1][di][dj] = fdot2f(wp, s.y, acc[1][di][dj]);
                    acc[2][di][dj] = fdot2f(wp, s.z, acc[2][di][dj]);
                    acc[3][di][dj] = fdot2f(wp, s.w, acc[3][di][dj]);
                    u += tg.w;
                }
            }
        }
    }

    #pragma unroll
    for (int bb = 0; bb < 4; ++bb) {
        float* ob = out + (size_t)(b + bb) * (NH * NH) + (size_t)pi * NH + pj;
        #pragma unroll
        for (int di = 0; di < 2; ++di)
            #pragma unroll
            for (int dj = 0; dj < 2; ++dj)
                unsafeAtomicAdd(ob + di * NH + dj, acc[bb][di][dj] * DPHI_F);
    }
}

// ---------------------------------------------------------------------------
extern "C" void kernel_launch(void* const* d_in, const int* in_sizes, int n_in,
                              void* d_out, int out_size, void* d_ws, size_t ws_size,
                              hipStream_t stream) {
    const float* sinos = (const float*)d_in[0];   // [32,720,512] f32
    const float* kern  = (const float*)d_in[1];   // [257] f32
    float* out = (float*)d_out;                   // [32,256,256] f32
    float* ws  = (float*)d_ws;

    // ws layout: [0,4096) f32 tables; [4096, +131072) Ht fp16 (512KB);
    // then padded filt f32 (23040 x 520 floats = 47.9MB).
    unsigned int*   Ht32 = (unsigned int*)(ws + 4096);
    unsigned short* Ht   = (unsigned short*)Ht32;
    float*          filt = ws + 4096 + 131072;

    hipLaunchKernelGGL(setup_kernel, dim3(323), dim3(256), 0, stream,
                       kern, ws, Ht32, (float4*)out, filt);
    hipLaunchKernelGGL(conv_gemm_kernel, dim3(23040 / 64), dim3(512), 0, stream,
                       sinos, Ht, filt);
    hipLaunchKernelGGL(backproject_kernel, dim3(4 * (NB / 4) * 64), dim3(256), 0, stream,
                       filt, ws, out);
}